// Round 1
// baseline (4378.963 us; speedup 1.0000x reference)
//
#include <hip/hip_runtime.h>

#define BB 4
#define SS 1024
#define DD 1024
#define HH 16
#define DH 64

// ---------------------------------------------------------------------------
// Linear VMP:  om[n][j] = sum_k x[n][k] * W[j][k]
//              ov[n][j] = sum_k W[j][k]^2 * vx[n][k] + vW[j][k]*(vx[n][k]+x[n][k]^2)
// 64x64 output tile per block, BK=16, 256 threads, 4x4 register blocking.
// ---------------------------------------------------------------------------
__global__ __launch_bounds__(256) void linear_vmp_kernel(
    const float* __restrict__ x, const float* __restrict__ vx,
    const float* __restrict__ W, const float* __restrict__ vW,
    float* __restrict__ om, float* __restrict__ ov)
{
    __shared__ float xA[64][17];
    __shared__ float vA[64][17];
    __shared__ float wB[64][17];
    __shared__ float vB[64][17];

    const int tid = threadIdx.x;
    const int ti = tid >> 4;          // 0..15 -> output row group
    const int tj = tid & 15;          // 0..15 -> output col group
    const int bm = blockIdx.y;        // 0..63  row tile of x
    const int bn = blockIdx.x;        // 0..15  row tile of W (= out col tile)
    const int lr = tid >> 2;          // 0..63  load row
    const int lc = (tid & 3) << 2;    // 0,4,8,12 load col (float4)

    float accm[4][4] = {{0.f,0.f,0.f,0.f},{0.f,0.f,0.f,0.f},{0.f,0.f,0.f,0.f},{0.f,0.f,0.f,0.f}};
    float accv[4][4] = {{0.f,0.f,0.f,0.f},{0.f,0.f,0.f,0.f},{0.f,0.f,0.f,0.f},{0.f,0.f,0.f,0.f}};

    const float* xg  = x  + (size_t)(bm * 64 + lr) * DD;
    const float* vxg = vx + (size_t)(bm * 64 + lr) * DD;
    const float* wg  = W  + (size_t)(bn * 64 + lr) * DD;
    const float* vwg = vW + (size_t)(bn * 64 + lr) * DD;

    for (int kk = 0; kk < DD; kk += 16) {
        float4 a4 = *(const float4*)(xg  + kk + lc);
        float4 b4 = *(const float4*)(vxg + kk + lc);
        float4 c4 = *(const float4*)(wg  + kk + lc);
        float4 d4 = *(const float4*)(vwg + kk + lc);
        xA[lr][lc+0] = a4.x; xA[lr][lc+1] = a4.y; xA[lr][lc+2] = a4.z; xA[lr][lc+3] = a4.w;
        vA[lr][lc+0] = b4.x; vA[lr][lc+1] = b4.y; vA[lr][lc+2] = b4.z; vA[lr][lc+3] = b4.w;
        wB[lr][lc+0] = c4.x; wB[lr][lc+1] = c4.y; wB[lr][lc+2] = c4.z; wB[lr][lc+3] = c4.w;
        vB[lr][lc+0] = d4.x; vB[lr][lc+1] = d4.y; vB[lr][lc+2] = d4.z; vB[lr][lc+3] = d4.w;
        __syncthreads();

        #pragma unroll
        for (int k = 0; k < 16; ++k) {
            float xr[4], vxr[4], pr[4];
            float wr[4], vwr[4], wsq[4];
            #pragma unroll
            for (int i = 0; i < 4; ++i) {
                xr[i]  = xA[ti*4+i][k];
                vxr[i] = vA[ti*4+i][k];
                pr[i]  = vxr[i] + xr[i]*xr[i];
            }
            #pragma unroll
            for (int j = 0; j < 4; ++j) {
                wr[j]  = wB[tj*4+j][k];
                vwr[j] = vB[tj*4+j][k];
                wsq[j] = wr[j]*wr[j];
            }
            #pragma unroll
            for (int i = 0; i < 4; ++i) {
                #pragma unroll
                for (int j = 0; j < 4; ++j) {
                    accm[i][j] += xr[i] * wr[j];
                    accv[i][j] += wsq[j] * vxr[i] + vwr[j] * pr[i];
                }
            }
        }
        __syncthreads();
    }

    #pragma unroll
    for (int i = 0; i < 4; ++i) {
        float* omp_ = om + (size_t)(bm*64 + ti*4 + i) * DD + bn*64 + tj*4;
        float* ovp_ = ov + (size_t)(bm*64 + ti*4 + i) * DD + bn*64 + tj*4;
        #pragma unroll
        for (int j = 0; j < 4; ++j) {
            omp_[j] = accm[i][j];
            ovp_[j] = accv[i][j];
        }
    }
}

// ---------------------------------------------------------------------------
// Fused attention VMP + residual.
// Grid (S/16, H, B); 256 threads = 16 q-rows x 16 key-lanes.
// Per key-block of 16: scores a,va -> e=exp(a) (no max needed: |a|<~1.5),
// exchange via LDS, accumulate moment sums T1..T5 + Z + E2V.
// o  = T1/Z
// vo = (T2 + sv*T4 + T5)/Z^2 - 2*T3/Z^3,  sv = E2V/Z^2
// ---------------------------------------------------------------------------
__global__ __launch_bounds__(256) void attn_vmp_kernel(
    const float* __restrict__ q,  const float* __restrict__ vq,
    const float* __restrict__ k,  const float* __restrict__ vk,
    const float* __restrict__ v,  const float* __restrict__ vv,
    const float* __restrict__ x,  const float* __restrict__ vx,
    float* __restrict__ om, float* __restrict__ ov)
{
    const int qt = blockIdx.x;   // q tile (16 rows)
    const int h  = blockIdx.y;
    const int b  = blockIdx.z;
    const int tid = threadIdx.x;
    const int tk = tid & 15;     // key lane / out-dim group
    const int tq = tid >> 4;     // q row within tile

    const size_t headoff = (size_t)b * SS * DD + (size_t)h * DH;

    __shared__ float q_s[16][68];
    __shared__ float vq_s[16][68];
    __shared__ float qs_s[16][68];
    __shared__ float k_s[16][68];   // reused for V
    __shared__ float vk_s[16][68];  // reused for VV
    __shared__ float kk_s[16][68];  // vk+k^2, reused for vv+v^2
    __shared__ float eb[16][17];
    __shared__ float e2vab[16][17];

    // stage Q tile (rows qt*16 .. +15)
    {
        const int r = tid >> 4;
        const int c = (tid & 15) << 2;
        const size_t g = headoff + (size_t)(qt*16 + r) * DD + c;
        float4 a4 = *(const float4*)(q + g);
        float4 b4 = *(const float4*)(vq + g);
        *(float4*)&q_s[r][c]  = a4;
        *(float4*)&vq_s[r][c] = b4;
        float4 s4; s4.x = a4.x*a4.x; s4.y = a4.y*a4.y; s4.z = a4.z*a4.z; s4.w = a4.w*a4.w;
        *(float4*)&qs_s[r][c] = s4;
    }
    __syncthreads();

    float T1[4] = {0.f,0.f,0.f,0.f};
    float T2[4] = {0.f,0.f,0.f,0.f};
    float T3[4] = {0.f,0.f,0.f,0.f};
    float T4[4] = {0.f,0.f,0.f,0.f};
    float T5[4] = {0.f,0.f,0.f,0.f};
    float Zp = 0.f, E2Vp = 0.f;

    const float inv_rd  = 0.03125f;        // 1/32
    const float inv_rd2 = 0.0009765625f;   // 1/1024

    for (int jb = 0; jb < SS/16; ++jb) {
        // stage K block
        {
            const int r = tid >> 4;
            const int c = (tid & 15) << 2;
            const size_t g = headoff + (size_t)(jb*16 + r) * DD + c;
            float4 a4 = *(const float4*)(k + g);
            float4 b4 = *(const float4*)(vk + g);
            *(float4*)&k_s[r][c]  = a4;
            *(float4*)&vk_s[r][c] = b4;
            float4 s4;
            s4.x = b4.x + a4.x*a4.x; s4.y = b4.y + a4.y*a4.y;
            s4.z = b4.z + a4.z*a4.z; s4.w = b4.w + a4.w*a4.w;
            *(float4*)&kk_s[r][c] = s4;
        }
        __syncthreads();

        float a = 0.f, va = 0.f;
        #pragma unroll 16
        for (int d = 0; d < DH; ++d) {
            float qd = q_s[tq][d];
            float kd = k_s[tk][d];
            a  += qd * kd;
            va += vq_s[tq][d] * kk_s[tk][d] + qs_s[tq][d] * vk_s[tk][d];
        }
        a  *= inv_rd;
        va *= inv_rd2;
        float e    = __expf(a);
        float e2va = e * e * va;
        Zp   += e;
        E2Vp += e2va;
        eb[tq][tk]    = e;
        e2vab[tq][tk] = e2va;
        __syncthreads();   // eb ready; done reading k_s

        // stage V block into the same buffers
        {
            const int r = tid >> 4;
            const int c = (tid & 15) << 2;
            const size_t g = headoff + (size_t)(jb*16 + r) * DD + c;
            float4 a4 = *(const float4*)(v + g);
            float4 b4 = *(const float4*)(vv + g);
            *(float4*)&k_s[r][c]  = a4;             // v
            *(float4*)&vk_s[r][c] = b4;             // vv
            float4 s4;
            s4.x = b4.x + a4.x*a4.x; s4.y = b4.y + a4.y*a4.y;
            s4.z = b4.z + a4.z*a4.z; s4.w = b4.w + a4.w*a4.w;
            *(float4*)&kk_s[r][c] = s4;             // vv + v^2
        }
        __syncthreads();

        const int dc = tk << 2;
        #pragma unroll 4
        for (int jj = 0; jj < 16; ++jj) {
            float e   = eb[tq][jj];
            float ev  = e2vab[tq][jj];
            float e2  = e * e;
            float e3v = e * ev;
            #pragma unroll
            for (int i = 0; i < 4; ++i) {
                float vd  = k_s[jj][dc+i];
                float vvd = vk_s[jj][dc+i];
                float wd  = kk_s[jj][dc+i];
                T1[i] += e   * vd;
                T2[i] += ev  * wd;
                T3[i] += e3v * wd;
                T4[i] += e2  * wd;
                T5[i] += e2  * vvd;
            }
        }
        __syncthreads();   // done reading V stage before next K overwrite
    }

    // reduce Z, E2V across the 16 lanes of this q-row group
    #pragma unroll
    for (int m = 1; m < 16; m <<= 1) {
        Zp   += __shfl_xor(Zp,   m, 16);
        E2Vp += __shfl_xor(E2Vp, m, 16);
    }
    const float invZ  = 1.f / Zp;
    const float invZ2 = invZ * invZ;
    const float sv    = E2Vp * invZ2;

    const size_t g = headoff + (size_t)(qt*16 + tq) * DD + (tk << 2);
    #pragma unroll
    for (int i = 0; i < 4; ++i) {
        float o  = T1[i] * invZ;
        float vo = (T2[i] + sv * T4[i] + T5[i]) * invZ2 - 2.f * T3[i] * invZ2 * invZ;
        om[g+i] = x[g+i]  + o;
        ov[g+i] = vx[g+i] + vo;
    }
}

extern "C" void kernel_launch(void* const* d_in, const int* in_sizes, int n_in,
                              void* d_out, int out_size, void* d_ws, size_t ws_size,
                              hipStream_t stream) {
    const float* x    = (const float*)d_in[0];
    const float* vx   = (const float*)d_in[1];
    const float* Wq   = (const float*)d_in[2];
    const float* vWq  = (const float*)d_in[3];
    const float* Wk   = (const float*)d_in[4];
    const float* vWk  = (const float*)d_in[5];
    const float* Wv   = (const float*)d_in[6];
    const float* vWv  = (const float*)d_in[7];

    const size_t NE = (size_t)BB * SS * DD;   // 4,194,304
    float* ws = (float*)d_ws;
    float* qm  = ws + 0*NE;
    float* qv  = ws + 1*NE;
    float* km  = ws + 2*NE;
    float* kv  = ws + 3*NE;
    float* vm  = ws + 4*NE;
    float* vvv = ws + 5*NE;

    float* om = (float*)d_out;
    float* ov = om + NE;

    dim3 gl(DD/64, (BB*SS)/64);   // (16, 64)
    linear_vmp_kernel<<<gl, 256, 0, stream>>>(x, vx, Wq, vWq, qm, qv);
    linear_vmp_kernel<<<gl, 256, 0, stream>>>(x, vx, Wk, vWk, km, kv);
    linear_vmp_kernel<<<gl, 256, 0, stream>>>(x, vx, Wv, vWv, vm, vvv);

    dim3 ga(SS/16, HH, BB);       // (64, 16, 4)
    attn_vmp_kernel<<<ga, 256, 0, stream>>>(qm, qv, km, kv, vm, vvv, x, vx, om, ov);
}

// Round 2
// 1876.171 us; speedup vs baseline: 2.3340x; 2.3340x over previous
//
#include <hip/hip_runtime.h>
#include <hip/hip_bf16.h>

#define BB 4
#define SS 1024
#define DD 1024
#define HH 16
#define DH 64
#define MM (BB*SS)   // 4096

typedef __attribute__((ext_vector_type(8))) short bf16x8;
typedef __attribute__((ext_vector_type(4))) float f32x4;

__device__ __forceinline__ float b2f(unsigned short u) {
    union { unsigned int i; float f; } c; c.i = ((unsigned int)u) << 16; return c.f;
}
__device__ __forceinline__ unsigned short f2b(float f) {
    __hip_bfloat16 h = __float2bfloat16(f);
    return *reinterpret_cast<unsigned short*>(&h);
}
__device__ __forceinline__ void gload16(const unsigned short* g, unsigned short* l) {
    __builtin_amdgcn_global_load_lds(
        (const __attribute__((address_space(1))) void*)g,
        (__attribute__((address_space(3))) void*)l,
        16, 0, 0);
}

// ---------------------------------------------------------------------------
// prep: fp32 -> bf16 conversions (+ squares / combined weight)
// ---------------------------------------------------------------------------
__global__ __launch_bounds__(256) void prep_x_kernel(
    const float* __restrict__ x, const float* __restrict__ vx,
    unsigned short* __restrict__ xb, unsigned short* __restrict__ vxb,
    unsigned short* __restrict__ xsb)
{
    const size_t i = ((size_t)blockIdx.x * 256 + threadIdx.x) * 4;
    float4 a = *(const float4*)(x + i);
    float4 b = *(const float4*)(vx + i);
    ushort4 oa = { f2b(a.x), f2b(a.y), f2b(a.z), f2b(a.w) };
    ushort4 ob = { f2b(b.x), f2b(b.y), f2b(b.z), f2b(b.w) };
    ushort4 os = { f2b(a.x*a.x), f2b(a.y*a.y), f2b(a.z*a.z), f2b(a.w*a.w) };
    *(ushort4*)(xb  + i) = oa;
    *(ushort4*)(vxb + i) = ob;
    *(ushort4*)(xsb + i) = os;
}

__global__ __launch_bounds__(256) void prep_w_kernel(
    const float* __restrict__ W, const float* __restrict__ vW,
    unsigned short* __restrict__ wb, unsigned short* __restrict__ wc,
    unsigned short* __restrict__ wv)
{
    const size_t i = ((size_t)blockIdx.x * 256 + threadIdx.x) * 4;
    float4 a = *(const float4*)(W + i);
    float4 b = *(const float4*)(vW + i);
    ushort4 oa = { f2b(a.x), f2b(a.y), f2b(a.z), f2b(a.w) };
    ushort4 oc = { f2b(a.x*a.x + b.x), f2b(a.y*a.y + b.y),
                   f2b(a.z*a.z + b.z), f2b(a.w*a.w + b.w) };
    ushort4 ov = { f2b(b.x), f2b(b.y), f2b(b.z), f2b(b.w) };
    *(ushort4*)(wb + i) = oa;
    *(ushort4*)(wc + i) = oc;
    *(ushort4*)(wv + i) = ov;
}

// ---------------------------------------------------------------------------
// Fused 3-GEMM projection VMP (bf16 MFMA, m97 structure):
//   m = xb @ Wb^T ; v = vxb @ Wc^T + xsb @ Wv^T   (Wc = W*W+vW, Wv = vW)
// 128x128 tile, BK=32, 256 thr = 4 waves (2x2), 16x16x32 bf16 MFMA.
// blockIdx.z in {0,1,2} selects the Q/K/V weight set & outputs.
// ---------------------------------------------------------------------------
__global__ __launch_bounds__(256) void gemm3_vmp_kernel(
    const unsigned short* __restrict__ xb, const unsigned short* __restrict__ vxb,
    const unsigned short* __restrict__ xsb,
    const unsigned short* __restrict__ w0b, const unsigned short* __restrict__ w0c,
    const unsigned short* __restrict__ w0v,
    const unsigned short* __restrict__ w1b, const unsigned short* __restrict__ w1c,
    const unsigned short* __restrict__ w1v,
    const unsigned short* __restrict__ w2b, const unsigned short* __restrict__ w2c,
    const unsigned short* __restrict__ w2v,
    unsigned short* __restrict__ o0m, unsigned short* __restrict__ o0v,
    unsigned short* __restrict__ o1m, unsigned short* __restrict__ o1v,
    unsigned short* __restrict__ o2m, unsigned short* __restrict__ o2v)
{
    __shared__ unsigned short sA[3][128*32];
    __shared__ unsigned short sB[3][128*32];

    const int z = blockIdx.z;
    const unsigned short* Wb = (z==0)? w0b : (z==1)? w1b : w2b;
    const unsigned short* Wc = (z==0)? w0c : (z==1)? w1c : w2c;
    const unsigned short* Wv = (z==0)? w0v : (z==1)? w1v : w2v;
    unsigned short* Om = (z==0)? o0m : (z==1)? o1m : o2m;
    unsigned short* Ov = (z==0)? o0v : (z==1)? o1v : o2v;

    const int bn = blockIdx.x;   // 0..7   (N tile)
    const int bm = blockIdx.y;   // 0..31  (M tile)
    const int tid = threadIdx.x;
    const int w = tid >> 6;      // wave 0..3
    const int l = tid & 63;      // lane
    const int wr = w >> 1, wc = w & 1;

    // staging: 512 16B-chunks per tile; chunk = row*4 + colchunk
    const int c0 = w*64 + l;
    const int r0 = c0 >> 2, cc0 = (c0 & 3) * 8;
    const int c1 = c0 + 256;
    const int r1 = c1 >> 2, cc1 = (c1 & 3) * 8;

    const unsigned short* Ag[3] = { xb, vxb, xsb };
    const unsigned short* Bg[3] = { Wb, Wc, Wv };

    const size_t aoff0 = (size_t)(bm*128 + r0) * DD + cc0;
    const size_t aoff1 = (size_t)(bm*128 + r1) * DD + cc1;
    const size_t boff0 = (size_t)(bn*128 + r0) * DD + cc0;
    const size_t boff1 = (size_t)(bn*128 + r1) * DD + cc1;

    const int lb0 = (w*64) * 8;         // LDS element offset, issue 0 (wave-uniform)
    const int lb1 = (256 + w*64) * 8;   // issue 1

    f32x4 accm[4][4];
    f32x4 accv[4][4];
    #pragma unroll
    for (int i = 0; i < 4; ++i)
        #pragma unroll
        for (int j = 0; j < 4; ++j) {
            accm[i][j] = (f32x4){0.f, 0.f, 0.f, 0.f};
            accv[i][j] = (f32x4){0.f, 0.f, 0.f, 0.f};
        }

    const int fr = l & 15;
    const int fk = (l >> 4) << 3;

    for (int kk = 0; kk < DD; kk += 32) {
        #pragma unroll
        for (int m = 0; m < 3; ++m) {
            gload16(Ag[m] + aoff0 + kk, &sA[m][lb0]);
            gload16(Ag[m] + aoff1 + kk, &sA[m][lb1]);
            gload16(Bg[m] + boff0 + kk, &sB[m][lb0]);
            gload16(Bg[m] + boff1 + kk, &sB[m][lb1]);
        }
        __syncthreads();

        bf16x8 bf0[4], bf1[4], bf2[4];
        #pragma unroll
        for (int j = 0; j < 4; ++j) {
            const int bo = (wc*64 + j*16 + fr)*32 + fk;
            bf0[j] = *(const bf16x8*)&sB[0][bo];
            bf1[j] = *(const bf16x8*)&sB[1][bo];
            bf2[j] = *(const bf16x8*)&sB[2][bo];
        }
        #pragma unroll
        for (int i = 0; i < 4; ++i) {
            const int ao = (wr*64 + i*16 + fr)*32 + fk;
            bf16x8 a0 = *(const bf16x8*)&sA[0][ao];
            bf16x8 a1 = *(const bf16x8*)&sA[1][ao];
            bf16x8 a2 = *(const bf16x8*)&sA[2][ao];
            #pragma unroll
            for (int j = 0; j < 4; ++j) {
                accm[i][j] = __builtin_amdgcn_mfma_f32_16x16x32_bf16(a0, bf0[j], accm[i][j], 0, 0, 0);
                accv[i][j] = __builtin_amdgcn_mfma_f32_16x16x32_bf16(a1, bf1[j], accv[i][j], 0, 0, 0);
                accv[i][j] = __builtin_amdgcn_mfma_f32_16x16x32_bf16(a2, bf2[j], accv[i][j], 0, 0, 0);
            }
        }
        __syncthreads();
    }

    // epilogue: C/D layout col=lane&15, row=(lane>>4)*4+r  (m89-verified)
    const int orow = bm*128 + wr*64 + ((l >> 4) << 2);
    const int ocol = bn*128 + wc*64 + fr;
    #pragma unroll
    for (int i = 0; i < 4; ++i)
        #pragma unroll
        for (int j = 0; j < 4; ++j)
            #pragma unroll
            for (int r = 0; r < 4; ++r) {
                const size_t off = (size_t)(orow + i*16 + r) * DD + ocol + j*16;
                Om[off] = f2b(accm[i][j][r]);
                Ov[off] = f2b(accv[i][j][r]);
            }
}

// ---------------------------------------------------------------------------
// Fused attention VMP + residual (fp32 compute, bf16 q/k/v inputs).
// Grid (S/16, H, B); 256 threads = 16 q-rows x 16 key-lanes.
// o  = T1/Z ;  vo = (T2 + sv*T4 + T5)/Z^2 - 2*T3/Z^3,  sv = E2V/Z^2
// ---------------------------------------------------------------------------
__global__ __launch_bounds__(256) void attn_vmp_kernel(
    const unsigned short* __restrict__ q,  const unsigned short* __restrict__ vq,
    const unsigned short* __restrict__ k,  const unsigned short* __restrict__ vk,
    const unsigned short* __restrict__ v,  const unsigned short* __restrict__ vv,
    const float* __restrict__ x,  const float* __restrict__ vx,
    float* __restrict__ om, float* __restrict__ ov)
{
    const int qt = blockIdx.x;
    const int h  = blockIdx.y;
    const int b  = blockIdx.z;
    const int tid = threadIdx.x;
    const int tk = tid & 15;
    const int tq = tid >> 4;

    const size_t headoff = (size_t)b * SS * DD + (size_t)h * DH;

    __shared__ float q_s[16][68];
    __shared__ float vq_s[16][68];
    __shared__ float qs_s[16][68];
    __shared__ float k_s[16][68];   // reused for V
    __shared__ float vk_s[16][68];  // reused for VV
    __shared__ float kk_s[16][68];  // vk+k^2, reused for vv+v^2
    __shared__ float eb[16][17];
    __shared__ float e2vab[16][17];

    {
        const int r = tid >> 4;
        const int c = (tid & 15) << 2;
        const size_t g = headoff + (size_t)(qt*16 + r) * DD + c;
        ushort4 a4 = *(const ushort4*)(q + g);
        ushort4 b4 = *(const ushort4*)(vq + g);
        float4 af = { b2f(a4.x), b2f(a4.y), b2f(a4.z), b2f(a4.w) };
        float4 bf_ = { b2f(b4.x), b2f(b4.y), b2f(b4.z), b2f(b4.w) };
        float4 sf = { af.x*af.x, af.y*af.y, af.z*af.z, af.w*af.w };
        *(float4*)&q_s[r][c]  = af;
        *(float4*)&vq_s[r][c] = bf_;
        *(float4*)&qs_s[r][c] = sf;
    }
    __syncthreads();

    float T1[4] = {0.f,0.f,0.f,0.f};
    float T2[4] = {0.f,0.f,0.f,0.f};
    float T3[4] = {0.f,0.f,0.f,0.f};
    float T4[4] = {0.f,0.f,0.f,0.f};
    float T5[4] = {0.f,0.f,0.f,0.f};
    float Zp = 0.f, E2Vp = 0.f;

    const float inv_rd  = 0.03125f;
    const float inv_rd2 = 0.0009765625f;

    for (int jb = 0; jb < SS/16; ++jb) {
        {
            const int r = tid >> 4;
            const int c = (tid & 15) << 2;
            const size_t g = headoff + (size_t)(jb*16 + r) * DD + c;
            ushort4 a4 = *(const ushort4*)(k + g);
            ushort4 b4 = *(const ushort4*)(vk + g);
            float4 af = { b2f(a4.x), b2f(a4.y), b2f(a4.z), b2f(a4.w) };
            float4 bf_ = { b2f(b4.x), b2f(b4.y), b2f(b4.z), b2f(b4.w) };
            float4 sf = { bf_.x + af.x*af.x, bf_.y + af.y*af.y,
                          bf_.z + af.z*af.z, bf_.w + af.w*af.w };
            *(float4*)&k_s[r][c]  = af;
            *(float4*)&vk_s[r][c] = bf_;
            *(float4*)&kk_s[r][c] = sf;
        }
        __syncthreads();

        float a = 0.f, va = 0.f;
        #pragma unroll 16
        for (int d = 0; d < DH; ++d) {
            float qd = q_s[tq][d];
            float kd = k_s[tk][d];
            a  += qd * kd;
            va += vq_s[tq][d] * kk_s[tk][d] + qs_s[tq][d] * vk_s[tk][d];
        }
        a  *= inv_rd;
        va *= inv_rd2;
        float e    = __expf(a);
        float e2va = e * e * va;
        Zp   += e;
        E2Vp += e2va;
        eb[tq][tk]    = e;
        e2vab[tq][tk] = e2va;
        __syncthreads();

        {
            const int r = tid >> 4;
            const int c = (tid & 15) << 2;
            const size_t g = headoff + (size_t)(jb*16 + r) * DD + c;
            ushort4 a4 = *(const ushort4*)(v + g);
            ushort4 b4 = *(const ushort4*)(vv + g);
            float4 af = { b2f(a4.x), b2f(a4.y), b2f(a4.z), b2f(a4.w) };
            float4 bf_ = { b2f(b4.x), b2f(b4.y), b2f(b4.z), b2f(b4.w) };
            float4 sf = { bf_.x + af.x*af.x, bf_.y + af.y*af.y,
                          bf_.z + af.z*af.z, bf_.w + af.w*af.w };
            *(float4*)&k_s[r][c]  = af;
            *(float4*)&vk_s[r][c] = bf_;
            *(float4*)&kk_s[r][c] = sf;
        }
        __syncthreads();

        const int dc = tk << 2;
        #pragma unroll 4
        for (int jj = 0; jj < 16; ++jj) {
            float e   = eb[tq][jj];
            float ev  = e2vab[tq][jj];
            float e2  = e * e;
            float e3v = e * ev;
            #pragma unroll
            for (int i = 0; i < 4; ++i) {
                float vd  = k_s[jj][dc+i];
                float vvd = vk_s[jj][dc+i];
                float wd  = kk_s[jj][dc+i];
                T1[i] += e   * vd;
                T2[i] += ev  * wd;
                T3[i] += e3v * wd;
                T4[i] += e2  * wd;
                T5[i] += e2  * vvd;
            }
        }
        __syncthreads();
    }

    #pragma unroll
    for (int m = 1; m < 16; m <<= 1) {
        Zp   += __shfl_xor(Zp,   m, 16);
        E2Vp += __shfl_xor(E2Vp, m, 16);
    }
    const float invZ  = 1.f / Zp;
    const float invZ2 = invZ * invZ;
    const float sv    = E2Vp * invZ2;

    const size_t g = headoff + (size_t)(qt*16 + tq) * DD + (tk << 2);
    #pragma unroll
    for (int i = 0; i < 4; ++i) {
        float o  = T1[i] * invZ;
        float vo = (T2[i] + sv * T4[i] + T5[i]) * invZ2 - 2.f * T3[i] * invZ2 * invZ;
        om[g+i] = x[g+i]  + o;
        ov[g+i] = vx[g+i] + vo;
    }
}

extern "C" void kernel_launch(void* const* d_in, const int* in_sizes, int n_in,
                              void* d_out, int out_size, void* d_ws, size_t ws_size,
                              hipStream_t stream) {
    const float* x    = (const float*)d_in[0];
    const float* vx   = (const float*)d_in[1];
    const float* Wq   = (const float*)d_in[2];
    const float* vWq  = (const float*)d_in[3];
    const float* Wk   = (const float*)d_in[4];
    const float* vWk  = (const float*)d_in[5];
    const float* Wv   = (const float*)d_in[6];
    const float* vWv  = (const float*)d_in[7];

    const size_t NE = (size_t)MM * DD;   // 4,194,304
    const size_t NW = (size_t)DD * DD;   // 1,048,576

    unsigned short* u = (unsigned short*)d_ws;
    unsigned short* qm   = u + 0*NE;
    unsigned short* qv   = u + 1*NE;
    unsigned short* km   = u + 2*NE;
    unsigned short* kv   = u + 3*NE;
    unsigned short* vm   = u + 4*NE;
    unsigned short* vvv  = u + 5*NE;
    unsigned short* xbb  = u + 6*NE;
    unsigned short* vxbb = u + 7*NE;
    unsigned short* xsbb = u + 8*NE;
    unsigned short* wp   = u + 9*NE;
    unsigned short* wqb = wp + 0*NW, *wqc = wp + 1*NW, *wqv = wp + 2*NW;
    unsigned short* wkb = wp + 3*NW, *wkc = wp + 4*NW, *wkv = wp + 5*NW;
    unsigned short* wvb = wp + 6*NW, *wvc = wp + 7*NW, *wvv = wp + 8*NW;

    float* om = (float*)d_out;
    float* ov = om + NE;

    prep_x_kernel<<<4096, 256, 0, stream>>>(x, vx, xbb, vxbb, xsbb);
    prep_w_kernel<<<1024, 256, 0, stream>>>(Wq, vWq, wqb, wqc, wqv);
    prep_w_kernel<<<1024, 256, 0, stream>>>(Wk, vWk, wkb, wkc, wkv);
    prep_w_kernel<<<1024, 256, 0, stream>>>(Wv, vWv, wvb, wvc, wvv);

    dim3 gg(8, 32, 3);
    gemm3_vmp_kernel<<<gg, 256, 0, stream>>>(xbb, vxbb, xsbb,
        wqb, wqc, wqv, wkb, wkc, wkv, wvb, wvc, wvv,
        qm, qv, km, kv, vm, vvv);

    dim3 ga(SS/16, HH, BB);
    attn_vmp_kernel<<<ga, 256, 0, stream>>>(qm, qv, km, kv, vm, vvv, x, vx, om, ov);
}

// Round 3
// 344.446 us; speedup vs baseline: 12.7131x; 5.4469x over previous
//
#include <hip/hip_runtime.h>
#include <hip/hip_bf16.h>

#define BB 4
#define SS 1024
#define DD 1024
#define HH 16
#define DH 64
#define MM (BB*SS)   // 4096

typedef __attribute__((ext_vector_type(8))) short bf16x8;
typedef __attribute__((ext_vector_type(8))) unsigned short u16x8;
typedef __attribute__((ext_vector_type(4))) float f32x4;

__device__ __forceinline__ float b2f(unsigned short u) {
    union { unsigned int i; float f; } c; c.i = ((unsigned int)u) << 16; return c.f;
}
__device__ __forceinline__ unsigned short f2b(float f) {
    __hip_bfloat16 h = __float2bfloat16(f);
    return *reinterpret_cast<unsigned short*>(&h);
}
__device__ __forceinline__ void gload16(const unsigned short* g, unsigned short* l) {
    __builtin_amdgcn_global_load_lds(
        (const __attribute__((address_space(1))) void*)g,
        (__attribute__((address_space(3))) void*)l,
        16, 0, 0);
}
#define MFMA16(a, b, c) __builtin_amdgcn_mfma_f32_16x16x32_bf16(a, b, c, 0, 0, 0)

// ---------------------------------------------------------------------------
// prep: fp32 -> bf16 conversions (+ squares / combined weight)
// ---------------------------------------------------------------------------
__global__ __launch_bounds__(256) void prep_x_kernel(
    const float* __restrict__ x, const float* __restrict__ vx,
    unsigned short* __restrict__ xb, unsigned short* __restrict__ vxb,
    unsigned short* __restrict__ xsb)
{
    const size_t i = ((size_t)blockIdx.x * 256 + threadIdx.x) * 4;
    float4 a = *(const float4*)(x + i);
    float4 b = *(const float4*)(vx + i);
    ushort4 oa = { f2b(a.x), f2b(a.y), f2b(a.z), f2b(a.w) };
    ushort4 ob = { f2b(b.x), f2b(b.y), f2b(b.z), f2b(b.w) };
    ushort4 os = { f2b(a.x*a.x), f2b(a.y*a.y), f2b(a.z*a.z), f2b(a.w*a.w) };
    *(ushort4*)(xb  + i) = oa;
    *(ushort4*)(vxb + i) = ob;
    *(ushort4*)(xsb + i) = os;
}

__global__ __launch_bounds__(256) void prep_w_kernel(
    const float* __restrict__ W, const float* __restrict__ vW,
    unsigned short* __restrict__ wb, unsigned short* __restrict__ wc,
    unsigned short* __restrict__ wv)
{
    const size_t i = ((size_t)blockIdx.x * 256 + threadIdx.x) * 4;
    float4 a = *(const float4*)(W + i);
    float4 b = *(const float4*)(vW + i);
    ushort4 oa = { f2b(a.x), f2b(a.y), f2b(a.z), f2b(a.w) };
    ushort4 oc = { f2b(a.x*a.x + b.x), f2b(a.y*a.y + b.y),
                   f2b(a.z*a.z + b.z), f2b(a.w*a.w + b.w) };
    ushort4 ov = { f2b(b.x), f2b(b.y), f2b(b.z), f2b(b.w) };
    *(ushort4*)(wb + i) = oa;
    *(ushort4*)(wc + i) = oc;
    *(ushort4*)(wv + i) = ov;
}

// ---------------------------------------------------------------------------
// Fused 3-GEMM projection VMP (bf16 MFMA, m97 structure) — unchanged (R2).
// ---------------------------------------------------------------------------
__global__ __launch_bounds__(256) void gemm3_vmp_kernel(
    const unsigned short* __restrict__ xb, const unsigned short* __restrict__ vxb,
    const unsigned short* __restrict__ xsb,
    const unsigned short* __restrict__ w0b, const unsigned short* __restrict__ w0c,
    const unsigned short* __restrict__ w0v,
    const unsigned short* __restrict__ w1b, const unsigned short* __restrict__ w1c,
    const unsigned short* __restrict__ w1v,
    const unsigned short* __restrict__ w2b, const unsigned short* __restrict__ w2c,
    const unsigned short* __restrict__ w2v,
    unsigned short* __restrict__ o0m, unsigned short* __restrict__ o0v,
    unsigned short* __restrict__ o1m, unsigned short* __restrict__ o1v,
    unsigned short* __restrict__ o2m, unsigned short* __restrict__ o2v)
{
    __shared__ unsigned short sA[3][128*32];
    __shared__ unsigned short sB[3][128*32];

    const int z = blockIdx.z;
    const unsigned short* Wb = (z==0)? w0b : (z==1)? w1b : w2b;
    const unsigned short* Wc = (z==0)? w0c : (z==1)? w1c : w2c;
    const unsigned short* Wv = (z==0)? w0v : (z==1)? w1v : w2v;
    unsigned short* Om = (z==0)? o0m : (z==1)? o1m : o2m;
    unsigned short* Ov = (z==0)? o0v : (z==1)? o1v : o2v;

    const int bn = blockIdx.x;
    const int bm = blockIdx.y;
    const int tid = threadIdx.x;
    const int w = tid >> 6;
    const int l = tid & 63;
    const int wr = w >> 1, wc = w & 1;

    const int c0 = w*64 + l;
    const int r0 = c0 >> 2, cc0 = (c0 & 3) * 8;
    const int c1 = c0 + 256;
    const int r1 = c1 >> 2, cc1 = (c1 & 3) * 8;

    const unsigned short* Ag[3] = { xb, vxb, xsb };
    const unsigned short* Bg[3] = { Wb, Wc, Wv };

    const size_t aoff0 = (size_t)(bm*128 + r0) * DD + cc0;
    const size_t aoff1 = (size_t)(bm*128 + r1) * DD + cc1;
    const size_t boff0 = (size_t)(bn*128 + r0) * DD + cc0;
    const size_t boff1 = (size_t)(bn*128 + r1) * DD + cc1;

    const int lb0 = (w*64) * 8;
    const int lb1 = (256 + w*64) * 8;

    f32x4 accm[4][4];
    f32x4 accv[4][4];
    #pragma unroll
    for (int i = 0; i < 4; ++i)
        #pragma unroll
        for (int j = 0; j < 4; ++j) {
            accm[i][j] = (f32x4){0.f, 0.f, 0.f, 0.f};
            accv[i][j] = (f32x4){0.f, 0.f, 0.f, 0.f};
        }

    const int fr = l & 15;
    const int fk = (l >> 4) << 3;

    for (int kk = 0; kk < DD; kk += 32) {
        #pragma unroll
        for (int m = 0; m < 3; ++m) {
            gload16(Ag[m] + aoff0 + kk, &sA[m][lb0]);
            gload16(Ag[m] + aoff1 + kk, &sA[m][lb1]);
            gload16(Bg[m] + boff0 + kk, &sB[m][lb0]);
            gload16(Bg[m] + boff1 + kk, &sB[m][lb1]);
        }
        __syncthreads();

        bf16x8 bf0[4], bf1[4], bf2[4];
        #pragma unroll
        for (int j = 0; j < 4; ++j) {
            const int bo = (wc*64 + j*16 + fr)*32 + fk;
            bf0[j] = *(const bf16x8*)&sB[0][bo];
            bf1[j] = *(const bf16x8*)&sB[1][bo];
            bf2[j] = *(const bf16x8*)&sB[2][bo];
        }
        #pragma unroll
        for (int i = 0; i < 4; ++i) {
            const int ao = (wr*64 + i*16 + fr)*32 + fk;
            bf16x8 a0 = *(const bf16x8*)&sA[0][ao];
            bf16x8 a1 = *(const bf16x8*)&sA[1][ao];
            bf16x8 a2 = *(const bf16x8*)&sA[2][ao];
            #pragma unroll
            for (int j = 0; j < 4; ++j) {
                accm[i][j] = MFMA16(a0, bf0[j], accm[i][j]);
                accv[i][j] = MFMA16(a1, bf1[j], accv[i][j]);
                accv[i][j] = MFMA16(a2, bf2[j], accv[i][j]);
            }
        }
        __syncthreads();
    }

    const int orow = bm*128 + wr*64 + ((l >> 4) << 2);
    const int ocol = bn*128 + wc*64 + fr;
    #pragma unroll
    for (int i = 0; i < 4; ++i)
        #pragma unroll
        for (int j = 0; j < 4; ++j)
            #pragma unroll
            for (int r = 0; r < 4; ++r) {
                const size_t off = (size_t)(orow + i*16 + r) * DD + ocol + j*16;
                Om[off] = f2b(accm[i][j][r]);
                Ov[off] = f2b(accv[i][j][r]);
            }
}

// ---------------------------------------------------------------------------
// prep_vt: transpose V-side to [B*H, DH, SS] and compute w = vv + v^2.
// Block = (jt, h, b) handles a [64 j][64 d] tile.
// ---------------------------------------------------------------------------
__global__ __launch_bounds__(256) void prep_vt_kernel(
    const unsigned short* __restrict__ vm, const unsigned short* __restrict__ vvv,
    unsigned short* __restrict__ vt, unsigned short* __restrict__ wt,
    unsigned short* __restrict__ vvt)
{
    __shared__ unsigned short tv[64][68];
    __shared__ unsigned short tw[64][68];
    __shared__ unsigned short tvv[64][68];
    const int t = threadIdx.x;
    const int jt = blockIdx.x, h = blockIdx.y, b = blockIdx.z;
    const size_t ibase = (size_t)b*SS*DD + (size_t)h*DH;
    {
        const int j = t & 63, cg = t >> 6;
        const size_t ga = ibase + (size_t)(jt*64 + j)*DD + cg*16;
        #pragma unroll
        for (int hh = 0; hh < 2; ++hh) {
            u16x8 v8  = *(const u16x8*)(vm  + ga + hh*8);
            u16x8 vv8 = *(const u16x8*)(vvv + ga + hh*8);
            u16x8 w8;
            #pragma unroll
            for (int e = 0; e < 8; ++e) {
                float vf = b2f(v8[e]);
                w8[e] = f2b(b2f(vv8[e]) + vf*vf);
            }
            *(u16x8*)&tv[j][cg*16 + hh*8]  = v8;
            *(u16x8*)&tvv[j][cg*16 + hh*8] = vv8;
            *(u16x8*)&tw[j][cg*16 + hh*8]  = w8;
        }
    }
    __syncthreads();
    {
        const int d = t >> 2, jq = t & 3;
        const size_t ob = (size_t)((b*HH + h)*DH + d)*SS + jt*64 + jq*16;
        u16x8 o0, o1, o2, o3, o4, o5;
        #pragma unroll
        for (int i = 0; i < 8; ++i) {
            o0[i] = tv[jq*16 + i][d];      o1[i] = tv[jq*16 + 8 + i][d];
            o2[i] = tw[jq*16 + i][d];      o3[i] = tw[jq*16 + 8 + i][d];
            o4[i] = tvv[jq*16 + i][d];     o5[i] = tvv[jq*16 + 8 + i][d];
        }
        *(u16x8*)(vt + ob)      = o0;  *(u16x8*)(vt + ob + 8)  = o1;
        *(u16x8*)(wt + ob)      = o2;  *(u16x8*)(wt + ob + 8)  = o3;
        *(u16x8*)(vvt + ob)     = o4;  *(u16x8*)(vvt + ob + 8) = o5;
    }
}

// kk = vk + k^2 (elementwise bf16)
__global__ __launch_bounds__(256) void prep_kk_kernel(
    const unsigned short* __restrict__ kmp, const unsigned short* __restrict__ kvp,
    unsigned short* __restrict__ kkb)
{
    const size_t i = ((size_t)blockIdx.x * 256 + threadIdx.x) * 8;
    u16x8 k8 = *(const u16x8*)(kmp + i);
    u16x8 v8 = *(const u16x8*)(kvp + i);
    u16x8 o8;
    #pragma unroll
    for (int e = 0; e < 8; ++e) {
        float kf = b2f(k8[e]);
        o8[e] = f2b(b2f(v8[e]) + kf*kf);
    }
    *(u16x8*)(kkb + i) = o8;
}

// ---------------------------------------------------------------------------
// MFMA attention VMP + residual.
// Grid (S/64, H, B); 4 waves; wave w owns q-rows [qt*64+w*16, +16).
// Per KV tile of 32: QK via 3 MFMA-GEMMs -> e,e2,ev,e3v into per-wave LDS ->
// PV via 5 MFMA-GEMMs + Z/E2V via ones-B MFMA (same C/D rows as T accs).
// K tiles: global_load_lds, source pre-swizzled (chunk ^= row&7), reads
// XOR-swizzled -> conflict-free. V tiles from transposed [d][j] globals,
// chunk ^= d&3. P: per-wave [16][36] padded (+2-way = free).
// ---------------------------------------------------------------------------
__global__ __launch_bounds__(256) void attn_mfma_kernel(
    const unsigned short* __restrict__ kmg, const unsigned short* __restrict__ kvg,
    const unsigned short* __restrict__ kkg,
    const unsigned short* __restrict__ vtg, const unsigned short* __restrict__ wtg,
    const unsigned short* __restrict__ vvtg,
    const unsigned short* __restrict__ qmg, const unsigned short* __restrict__ qvg,
    const float* __restrict__ x, const float* __restrict__ vx,
    float* __restrict__ om, float* __restrict__ ov)
{
    __shared__ unsigned short Ks[3][32*64];
    __shared__ unsigned short Vs[3][64*32];
    __shared__ unsigned short Ps[4][4][16*36];

    const int tid = threadIdx.x;
    const int w = tid >> 6, l = tid & 63;
    const int lo = l & 15, hi = l >> 4;
    const int qt = blockIdx.x, h = blockIdx.y, b = blockIdx.z;
    const size_t xbase = (size_t)b*SS*DD + (size_t)h*DH;
    const size_t vbase = (size_t)(b*HH + h)*DH*SS;

    // Q A-fragments (hoisted, direct from global)
    bf16x8 qA[2], vqA[2], qsA[2];
    {
        const int qrow = qt*64 + w*16 + lo;
        #pragma unroll
        for (int ks = 0; ks < 2; ++ks) {
            const size_t ga = xbase + (size_t)qrow*DD + ks*32 + hi*8;
            qA[ks]  = *(const bf16x8*)(qmg + ga);
            vqA[ks] = *(const bf16x8*)(qvg + ga);
            #pragma unroll
            for (int e = 0; e < 8; ++e) {
                float f = b2f((unsigned short)qA[ks][e]);
                qsA[ks][e] = (short)f2b(f*f);
            }
        }
    }
    bf16x8 onesB;
    #pragma unroll
    for (int e = 0; e < 8; ++e) onesB[e] = (short)0x3F80;

    f32x4 T1[4], T2[4], T3[4], T4[4], T5[4];
    f32x4 zac = {0.f,0.f,0.f,0.f}, e2vac = {0.f,0.f,0.f,0.f};
    #pragma unroll
    for (int cb = 0; cb < 4; ++cb) {
        T1[cb] = (f32x4){0.f,0.f,0.f,0.f};
        T2[cb] = (f32x4){0.f,0.f,0.f,0.f};
        T3[cb] = (f32x4){0.f,0.f,0.f,0.f};
        T4[cb] = (f32x4){0.f,0.f,0.f,0.f};
        T5[cb] = (f32x4){0.f,0.f,0.f,0.f};
    }

    // per-lane pre-swizzled staging source offsets
    const size_t koff = (size_t)(l >> 3)*DD + (size_t)(((l & 7) ^ ((l >> 3) & 7)) * 8);
    const size_t voff = (size_t)(l >> 2)*SS + (size_t)(((l & 3) ^ ((l >> 2) & 3)) * 8);

    for (int t = 0; t < SS/32; ++t) {
        const size_t j0 = (size_t)t * 32;
        #define IK(m, p, G) gload16(G + xbase + (j0 + (p)*8)*DD + koff, &Ks[m][(p)*512])
        #define IV(m, p, G) gload16(G + vbase + (size_t)((p)*16)*SS + j0 + voff, &Vs[m][(p)*512])
        if (w == 0)      { IK(0,0,kmg); IK(0,1,kmg); IK(0,2,kmg); IK(0,3,kmg); IK(1,0,kvg); IK(1,1,kvg); }
        else if (w == 1) { IK(1,2,kvg); IK(1,3,kvg); IK(2,0,kkg); IK(2,1,kkg); IK(2,2,kkg); IK(2,3,kkg); }
        else if (w == 2) { IV(0,0,vtg); IV(0,1,vtg); IV(0,2,vtg); IV(0,3,vtg); IV(1,0,wtg); IV(1,1,wtg); }
        else             { IV(1,2,wtg); IV(1,3,wtg); IV(2,0,vvtg); IV(2,1,vvtg); IV(2,2,vvtg); IV(2,3,vvtg); }
        __syncthreads();

        // QK + moments
        #pragma unroll
        for (int jb = 0; jb < 2; ++jb) {
            f32x4 aa = {0.f,0.f,0.f,0.f}, vva = {0.f,0.f,0.f,0.f};
            const int j = jb*16 + lo;
            #pragma unroll
            for (int ks = 0; ks < 2; ++ks) {
                const int co = j*64 + (((ks*4 + hi) ^ (j & 7)) * 8);
                bf16x8 kB  = *(const bf16x8*)&Ks[0][co];
                bf16x8 vkB = *(const bf16x8*)&Ks[1][co];
                bf16x8 kkB = *(const bf16x8*)&Ks[2][co];
                aa  = MFMA16(qA[ks],  kB,  aa);
                vva = MFMA16(vqA[ks], kkB, vva);
                vva = MFMA16(qsA[ks], vkB, vva);
            }
            #pragma unroll
            for (int r = 0; r < 4; ++r) {
                float a  = aa[r]  * 0.03125f;
                float va = vva[r] * 0.0009765625f;
                float e  = __expf(a);
                float e2 = e*e;
                float ev = e2*va;
                float e3 = ev*e;
                const int pb = (hi*4 + r)*36 + jb*16 + lo;
                Ps[w][0][pb] = f2b(e);
                Ps[w][1][pb] = f2b(e2);
                Ps[w][2][pb] = f2b(ev);
                Ps[w][3][pb] = f2b(e3);
            }
        }

        // PV
        {
            const int pa = lo*36 + hi*8;
            bf16x8 eA  = *(const bf16x8*)&Ps[w][0][pa];
            bf16x8 e2A = *(const bf16x8*)&Ps[w][1][pa];
            bf16x8 evA = *(const bf16x8*)&Ps[w][2][pa];
            bf16x8 e3A = *(const bf16x8*)&Ps[w][3][pa];
            zac   = MFMA16(eA,  onesB, zac);
            e2vac = MFMA16(evA, onesB, e2vac);
            #pragma unroll
            for (int cb = 0; cb < 4; ++cb) {
                const int d = cb*16 + lo;
                const int vo_ = d*32 + ((hi ^ (d & 3)) * 8);
                bf16x8 vB  = *(const bf16x8*)&Vs[0][vo_];
                bf16x8 wB  = *(const bf16x8*)&Vs[1][vo_];
                bf16x8 vvB = *(const bf16x8*)&Vs[2][vo_];
                T1[cb] = MFMA16(eA,  vB,  T1[cb]);
                T2[cb] = MFMA16(evA, wB,  T2[cb]);
                T3[cb] = MFMA16(e3A, wB,  T3[cb]);
                T4[cb] = MFMA16(e2A, wB,  T4[cb]);
                T5[cb] = MFMA16(e2A, vvB, T5[cb]);
            }
        }
        __syncthreads();
    }

    // epilogue: C/D row = hi*4+r matches across zac/e2vac/T accs
    #pragma unroll
    for (int r = 0; r < 4; ++r) {
        const float Z     = zac[r];
        const float invZ  = 1.f / Z;
        const float invZ2 = invZ * invZ;
        const float sv    = e2vac[r] * invZ2;
        const int row = qt*64 + w*16 + hi*4 + r;
        #pragma unroll
        for (int cb = 0; cb < 4; ++cb) {
            const size_t gi = xbase + (size_t)row*DD + cb*16 + lo;
            const float o  = T1[cb][r] * invZ;
            const float vo = (T2[cb][r] + sv*T4[cb][r] + T5[cb][r]) * invZ2
                           - 2.f * T3[cb][r] * invZ2 * invZ;
            om[gi] = x[gi] + o;
            ov[gi] = vx[gi] + vo;
        }
    }
}

extern "C" void kernel_launch(void* const* d_in, const int* in_sizes, int n_in,
                              void* d_out, int out_size, void* d_ws, size_t ws_size,
                              hipStream_t stream) {
    const float* x    = (const float*)d_in[0];
    const float* vx   = (const float*)d_in[1];
    const float* Wq   = (const float*)d_in[2];
    const float* vWq  = (const float*)d_in[3];
    const float* Wk   = (const float*)d_in[4];
    const float* vWk  = (const float*)d_in[5];
    const float* Wv   = (const float*)d_in[6];
    const float* vWv  = (const float*)d_in[7];

    const size_t NE = (size_t)MM * DD;
    const size_t NW = (size_t)DD * DD;

    unsigned short* u = (unsigned short*)d_ws;
    unsigned short* qm   = u + 0*NE;
    unsigned short* qv   = u + 1*NE;
    unsigned short* km   = u + 2*NE;
    unsigned short* kv   = u + 3*NE;
    unsigned short* vm   = u + 4*NE;
    unsigned short* vvv  = u + 5*NE;
    unsigned short* xbb  = u + 6*NE;   // after gemm3: reused as vt
    unsigned short* vxbb = u + 7*NE;   // after gemm3: reused as wt
    unsigned short* xsbb = u + 8*NE;   // after gemm3: reused as vvt
    unsigned short* wp   = u + 9*NE;   // weights; after gemm3: reused as kk
    unsigned short* wqb = wp + 0*NW, *wqc = wp + 1*NW, *wqv = wp + 2*NW;
    unsigned short* wkb = wp + 3*NW, *wkc = wp + 4*NW, *wkv = wp + 5*NW;
    unsigned short* wvb = wp + 6*NW, *wvc = wp + 7*NW, *wvv = wp + 8*NW;

    float* om = (float*)d_out;
    float* ov = om + NE;

    prep_x_kernel<<<4096, 256, 0, stream>>>(x, vx, xbb, vxbb, xsbb);
    prep_w_kernel<<<1024, 256, 0, stream>>>(Wq, vWq, wqb, wqc, wqv);
    prep_w_kernel<<<1024, 256, 0, stream>>>(Wk, vWk, wkb, wkc, wkv);
    prep_w_kernel<<<1024, 256, 0, stream>>>(Wv, vWv, wvb, wvc, wvv);

    dim3 gg(8, 32, 3);
    gemm3_vmp_kernel<<<gg, 256, 0, stream>>>(xbb, vxbb, xsbb,
        wqb, wqc, wqv, wkb, wkc, wkv, wvb, wvc, wvv,
        qm, qv, km, kv, vm, vvv);

    // V-side transpose (+ w=vv+v^2) into dead prep-x regions; kk into dead weights
    unsigned short* vt  = xbb;
    unsigned short* wt  = vxbb;
    unsigned short* vvt = xsbb;
    unsigned short* kkb = wp;
    dim3 gt(SS/64, HH, BB);
    prep_vt_kernel<<<gt, 256, 0, stream>>>(vm, vvv, vt, wt, vvt);
    prep_kk_kernel<<<2048, 256, 0, stream>>>(km, kv, kkb);

    dim3 ga(SS/64, HH, BB);
    attn_mfma_kernel<<<ga, 256, 0, stream>>>(km, kv, kkb, vt, wt, vvt,
                                             qm, qv, x, vx, om, ov);
}

// Round 4
// 300.376 us; speedup vs baseline: 14.5783x; 1.1467x over previous
//
#include <hip/hip_runtime.h>
#include <hip/hip_bf16.h>

#define BB 4
#define SS 1024
#define DD 1024
#define HH 16
#define DH 64
#define MM (BB*SS)   // 4096

typedef __attribute__((ext_vector_type(8))) short bf16x8;
typedef __attribute__((ext_vector_type(8))) unsigned short u16x8;
typedef __attribute__((ext_vector_type(4))) float f32x4;

__device__ __forceinline__ float b2f(unsigned short u) {
    union { unsigned int i; float f; } c; c.i = ((unsigned int)u) << 16; return c.f;
}
__device__ __forceinline__ unsigned short f2b(float f) {
    __hip_bfloat16 h = __float2bfloat16(f);
    return *reinterpret_cast<unsigned short*>(&h);
}
__device__ __forceinline__ void gload16(const unsigned short* g, unsigned short* l) {
    __builtin_amdgcn_global_load_lds(
        (const __attribute__((address_space(1))) void*)g,
        (__attribute__((address_space(3))) void*)l,
        16, 0, 0);
}
#define MFMA16(a, b, c) __builtin_amdgcn_mfma_f32_16x16x32_bf16(a, b, c, 0, 0, 0)

// ---------------------------------------------------------------------------
// prep: fp32 -> bf16 conversions (+ squares / combined weight)
// ---------------------------------------------------------------------------
__global__ __launch_bounds__(256) void prep_x_kernel(
    const float* __restrict__ x, const float* __restrict__ vx,
    unsigned short* __restrict__ xb, unsigned short* __restrict__ vxb,
    unsigned short* __restrict__ xsb)
{
    const size_t i = ((size_t)blockIdx.x * 256 + threadIdx.x) * 4;
    float4 a = *(const float4*)(x + i);
    float4 b = *(const float4*)(vx + i);
    ushort4 oa = { f2b(a.x), f2b(a.y), f2b(a.z), f2b(a.w) };
    ushort4 ob = { f2b(b.x), f2b(b.y), f2b(b.z), f2b(b.w) };
    ushort4 os = { f2b(a.x*a.x), f2b(a.y*a.y), f2b(a.z*a.z), f2b(a.w*a.w) };
    *(ushort4*)(xb  + i) = oa;
    *(ushort4*)(vxb + i) = ob;
    *(ushort4*)(xsb + i) = os;
}

__global__ __launch_bounds__(256) void prep_w_kernel(
    const float* __restrict__ W, const float* __restrict__ vW,
    unsigned short* __restrict__ wb, unsigned short* __restrict__ wc,
    unsigned short* __restrict__ wv)
{
    const size_t i = ((size_t)blockIdx.x * 256 + threadIdx.x) * 4;
    float4 a = *(const float4*)(W + i);
    float4 b = *(const float4*)(vW + i);
    ushort4 oa = { f2b(a.x), f2b(a.y), f2b(a.z), f2b(a.w) };
    ushort4 oc = { f2b(a.x*a.x + b.x), f2b(a.y*a.y + b.y),
                   f2b(a.z*a.z + b.z), f2b(a.w*a.w + b.w) };
    ushort4 ov = { f2b(b.x), f2b(b.y), f2b(b.z), f2b(b.w) };
    *(ushort4*)(wb + i) = oa;
    *(ushort4*)(wc + i) = oc;
    *(ushort4*)(wv + i) = ov;
}

// ---------------------------------------------------------------------------
// Mean GEMM: m = xb @ Wb^T  (m97 structure: 128x128 tile, BK=32, 4 waves)
// blockIdx.z selects Q/K/V weights+output.
// ---------------------------------------------------------------------------
__global__ __launch_bounds__(256) void gemm_mean_kernel(
    const unsigned short* __restrict__ xb,
    const unsigned short* __restrict__ w0b, const unsigned short* __restrict__ w1b,
    const unsigned short* __restrict__ w2b,
    unsigned short* __restrict__ o0m, unsigned short* __restrict__ o1m,
    unsigned short* __restrict__ o2m)
{
    __shared__ unsigned short sA[128*32];
    __shared__ unsigned short sB[128*32];

    const int z = blockIdx.z;
    const unsigned short* Wb = (z==0)? w0b : (z==1)? w1b : w2b;
    unsigned short* Om = (z==0)? o0m : (z==1)? o1m : o2m;

    const int bn = blockIdx.x;
    const int bm = blockIdx.y;
    const int tid = threadIdx.x;
    const int w = tid >> 6;
    const int l = tid & 63;
    const int wr = w >> 1, wc = w & 1;

    const int c0 = w*64 + l;
    const int r0 = c0 >> 2, cc0 = (c0 & 3) * 8;
    const int c1 = c0 + 256;
    const int r1 = c1 >> 2, cc1 = (c1 & 3) * 8;

    const size_t aoff0 = (size_t)(bm*128 + r0) * DD + cc0;
    const size_t aoff1 = (size_t)(bm*128 + r1) * DD + cc1;
    const size_t boff0 = (size_t)(bn*128 + r0) * DD + cc0;
    const size_t boff1 = (size_t)(bn*128 + r1) * DD + cc1;

    const int lb0 = (w*64) * 8;
    const int lb1 = (256 + w*64) * 8;

    f32x4 acc[4][4];
    #pragma unroll
    for (int i = 0; i < 4; ++i)
        #pragma unroll
        for (int j = 0; j < 4; ++j)
            acc[i][j] = (f32x4){0.f,0.f,0.f,0.f};

    const int fr = l & 15;
    const int fk = (l >> 4) << 3;

    for (int kk = 0; kk < DD; kk += 32) {
        gload16(xb + aoff0 + kk, &sA[lb0]);
        gload16(xb + aoff1 + kk, &sA[lb1]);
        gload16(Wb + boff0 + kk, &sB[lb0]);
        gload16(Wb + boff1 + kk, &sB[lb1]);
        __syncthreads();

        bf16x8 bfr[4];
        #pragma unroll
        for (int j = 0; j < 4; ++j)
            bfr[j] = *(const bf16x8*)&sB[(wc*64 + j*16 + fr)*32 + fk];
        #pragma unroll
        for (int i = 0; i < 4; ++i) {
            bf16x8 a0 = *(const bf16x8*)&sA[(wr*64 + i*16 + fr)*32 + fk];
            #pragma unroll
            for (int j = 0; j < 4; ++j)
                acc[i][j] = MFMA16(a0, bfr[j], acc[i][j]);
        }
        __syncthreads();
    }

    const int orow = bm*128 + wr*64 + ((l >> 4) << 2);
    const int ocol = bn*128 + wc*64 + fr;
    #pragma unroll
    for (int i = 0; i < 4; ++i)
        #pragma unroll
        for (int j = 0; j < 4; ++j)
            #pragma unroll
            for (int r = 0; r < 4; ++r)
                Om[(size_t)(orow + i*16 + r) * DD + ocol + j*16] = f2b(acc[i][j][r]);
}

// ---------------------------------------------------------------------------
// Var GEMM: v = vxb @ Wc^T + xsb @ Wv^T  (dual chain, single accumulator)
// ---------------------------------------------------------------------------
__global__ __launch_bounds__(256) void gemm_var_kernel(
    const unsigned short* __restrict__ vxb, const unsigned short* __restrict__ xsb,
    const unsigned short* __restrict__ w0c, const unsigned short* __restrict__ w0v,
    const unsigned short* __restrict__ w1c, const unsigned short* __restrict__ w1v,
    const unsigned short* __restrict__ w2c, const unsigned short* __restrict__ w2v,
    unsigned short* __restrict__ o0v, unsigned short* __restrict__ o1v,
    unsigned short* __restrict__ o2v)
{
    __shared__ unsigned short sA1[128*32];
    __shared__ unsigned short sA2[128*32];
    __shared__ unsigned short sB1[128*32];
    __shared__ unsigned short sB2[128*32];

    const int z = blockIdx.z;
    const unsigned short* Wc = (z==0)? w0c : (z==1)? w1c : w2c;
    const unsigned short* Wv = (z==0)? w0v : (z==1)? w1v : w2v;
    unsigned short* Ov = (z==0)? o0v : (z==1)? o1v : o2v;

    const int bn = blockIdx.x;
    const int bm = blockIdx.y;
    const int tid = threadIdx.x;
    const int w = tid >> 6;
    const int l = tid & 63;
    const int wr = w >> 1, wc = w & 1;

    const int c0 = w*64 + l;
    const int r0 = c0 >> 2, cc0 = (c0 & 3) * 8;
    const int c1 = c0 + 256;
    const int r1 = c1 >> 2, cc1 = (c1 & 3) * 8;

    const size_t aoff0 = (size_t)(bm*128 + r0) * DD + cc0;
    const size_t aoff1 = (size_t)(bm*128 + r1) * DD + cc1;
    const size_t boff0 = (size_t)(bn*128 + r0) * DD + cc0;
    const size_t boff1 = (size_t)(bn*128 + r1) * DD + cc1;

    const int lb0 = (w*64) * 8;
    const int lb1 = (256 + w*64) * 8;

    f32x4 acc[4][4];
    #pragma unroll
    for (int i = 0; i < 4; ++i)
        #pragma unroll
        for (int j = 0; j < 4; ++j)
            acc[i][j] = (f32x4){0.f,0.f,0.f,0.f};

    const int fr = l & 15;
    const int fk = (l >> 4) << 3;

    for (int kk = 0; kk < DD; kk += 32) {
        gload16(vxb + aoff0 + kk, &sA1[lb0]);
        gload16(vxb + aoff1 + kk, &sA1[lb1]);
        gload16(xsb + aoff0 + kk, &sA2[lb0]);
        gload16(xsb + aoff1 + kk, &sA2[lb1]);
        gload16(Wc + boff0 + kk, &sB1[lb0]);
        gload16(Wc + boff1 + kk, &sB1[lb1]);
        gload16(Wv + boff0 + kk, &sB2[lb0]);
        gload16(Wv + boff1 + kk, &sB2[lb1]);
        __syncthreads();

        bf16x8 bc[4], bv[4];
        #pragma unroll
        for (int j = 0; j < 4; ++j) {
            const int bo = (wc*64 + j*16 + fr)*32 + fk;
            bc[j] = *(const bf16x8*)&sB1[bo];
            bv[j] = *(const bf16x8*)&sB2[bo];
        }
        #pragma unroll
        for (int i = 0; i < 4; ++i) {
            const int ao = (wr*64 + i*16 + fr)*32 + fk;
            bf16x8 a1 = *(const bf16x8*)&sA1[ao];
            bf16x8 a2 = *(const bf16x8*)&sA2[ao];
            #pragma unroll
            for (int j = 0; j < 4; ++j) {
                acc[i][j] = MFMA16(a1, bc[j], acc[i][j]);
                acc[i][j] = MFMA16(a2, bv[j], acc[i][j]);
            }
        }
        __syncthreads();
    }

    const int orow = bm*128 + wr*64 + ((l >> 4) << 2);
    const int ocol = bn*128 + wc*64 + fr;
    #pragma unroll
    for (int i = 0; i < 4; ++i)
        #pragma unroll
        for (int j = 0; j < 4; ++j)
            #pragma unroll
            for (int r = 0; r < 4; ++r)
                Ov[(size_t)(orow + i*16 + r) * DD + ocol + j*16] = f2b(acc[i][j][r]);
}

// ---------------------------------------------------------------------------
// prep_vt: transpose V-side to [B*H, DH, SS] and compute w = vv + v^2.
// ---------------------------------------------------------------------------
__global__ __launch_bounds__(256) void prep_vt_kernel(
    const unsigned short* __restrict__ vm, const unsigned short* __restrict__ vvv,
    unsigned short* __restrict__ vt, unsigned short* __restrict__ wt,
    unsigned short* __restrict__ vvt)
{
    __shared__ unsigned short tv[64][68];
    __shared__ unsigned short tw[64][68];
    __shared__ unsigned short tvv[64][68];
    const int t = threadIdx.x;
    const int jt = blockIdx.x, h = blockIdx.y, b = blockIdx.z;
    const size_t ibase = (size_t)b*SS*DD + (size_t)h*DH;
    {
        const int j = t & 63, cg = t >> 6;
        const size_t ga = ibase + (size_t)(jt*64 + j)*DD + cg*16;
        #pragma unroll
        for (int hh = 0; hh < 2; ++hh) {
            u16x8 v8  = *(const u16x8*)(vm  + ga + hh*8);
            u16x8 vv8 = *(const u16x8*)(vvv + ga + hh*8);
            u16x8 w8;
            #pragma unroll
            for (int e = 0; e < 8; ++e) {
                float vf = b2f(v8[e]);
                w8[e] = f2b(b2f(vv8[e]) + vf*vf);
            }
            *(u16x8*)&tv[j][cg*16 + hh*8]  = v8;
            *(u16x8*)&tvv[j][cg*16 + hh*8] = vv8;
            *(u16x8*)&tw[j][cg*16 + hh*8]  = w8;
        }
    }
    __syncthreads();
    {
        const int d = t >> 2, jq = t & 3;
        const size_t ob = (size_t)((b*HH + h)*DH + d)*SS + jt*64 + jq*16;
        u16x8 o0, o1, o2, o3, o4, o5;
        #pragma unroll
        for (int i = 0; i < 8; ++i) {
            o0[i] = tv[jq*16 + i][d];      o1[i] = tv[jq*16 + 8 + i][d];
            o2[i] = tw[jq*16 + i][d];      o3[i] = tw[jq*16 + 8 + i][d];
            o4[i] = tvv[jq*16 + i][d];     o5[i] = tvv[jq*16 + 8 + i][d];
        }
        *(u16x8*)(vt + ob)      = o0;  *(u16x8*)(vt + ob + 8)  = o1;
        *(u16x8*)(wt + ob)      = o2;  *(u16x8*)(wt + ob + 8)  = o3;
        *(u16x8*)(vvt + ob)     = o4;  *(u16x8*)(vvt + ob + 8) = o5;
    }
}

// kk = vk + k^2 (elementwise bf16)
__global__ __launch_bounds__(256) void prep_kk_kernel(
    const unsigned short* __restrict__ kmp, const unsigned short* __restrict__ kvp,
    unsigned short* __restrict__ kkb)
{
    const size_t i = ((size_t)blockIdx.x * 256 + threadIdx.x) * 8;
    u16x8 k8 = *(const u16x8*)(kmp + i);
    u16x8 v8 = *(const u16x8*)(kvp + i);
    u16x8 o8;
    #pragma unroll
    for (int e = 0; e < 8; ++e) {
        float kf = b2f(k8[e]);
        o8[e] = f2b(b2f(v8[e]) + kf*kf);
    }
    *(u16x8*)(kkb + i) = o8;
}

// ---------------------------------------------------------------------------
// MFMA attention VMP + residual (unchanged from R3).
// ---------------------------------------------------------------------------
__global__ __launch_bounds__(256) void attn_mfma_kernel(
    const unsigned short* __restrict__ kmg, const unsigned short* __restrict__ kvg,
    const unsigned short* __restrict__ kkg,
    const unsigned short* __restrict__ vtg, const unsigned short* __restrict__ wtg,
    const unsigned short* __restrict__ vvtg,
    const unsigned short* __restrict__ qmg, const unsigned short* __restrict__ qvg,
    const float* __restrict__ x, const float* __restrict__ vx,
    float* __restrict__ om, float* __restrict__ ov)
{
    __shared__ unsigned short Ks[3][32*64];
    __shared__ unsigned short Vs[3][64*32];
    __shared__ unsigned short Ps[4][4][16*36];

    const int tid = threadIdx.x;
    const int w = tid >> 6, l = tid & 63;
    const int lo = l & 15, hi = l >> 4;
    const int qt = blockIdx.x, h = blockIdx.y, b = blockIdx.z;
    const size_t xbase = (size_t)b*SS*DD + (size_t)h*DH;
    const size_t vbase = (size_t)(b*HH + h)*DH*SS;

    bf16x8 qA[2], vqA[2], qsA[2];
    {
        const int qrow = qt*64 + w*16 + lo;
        #pragma unroll
        for (int ks = 0; ks < 2; ++ks) {
            const size_t ga = xbase + (size_t)qrow*DD + ks*32 + hi*8;
            qA[ks]  = *(const bf16x8*)(qmg + ga);
            vqA[ks] = *(const bf16x8*)(qvg + ga);
            #pragma unroll
            for (int e = 0; e < 8; ++e) {
                float f = b2f((unsigned short)qA[ks][e]);
                qsA[ks][e] = (short)f2b(f*f);
            }
        }
    }
    bf16x8 onesB;
    #pragma unroll
    for (int e = 0; e < 8; ++e) onesB[e] = (short)0x3F80;

    f32x4 T1[4], T2[4], T3[4], T4[4], T5[4];
    f32x4 zac = {0.f,0.f,0.f,0.f}, e2vac = {0.f,0.f,0.f,0.f};
    #pragma unroll
    for (int cb = 0; cb < 4; ++cb) {
        T1[cb] = (f32x4){0.f,0.f,0.f,0.f};
        T2[cb] = (f32x4){0.f,0.f,0.f,0.f};
        T3[cb] = (f32x4){0.f,0.f,0.f,0.f};
        T4[cb] = (f32x4){0.f,0.f,0.f,0.f};
        T5[cb] = (f32x4){0.f,0.f,0.f,0.f};
    }

    const size_t koff = (size_t)(l >> 3)*DD + (size_t)(((l & 7) ^ ((l >> 3) & 7)) * 8);
    const size_t voff = (size_t)(l >> 2)*SS + (size_t)(((l & 3) ^ ((l >> 2) & 3)) * 8);

    for (int t = 0; t < SS/32; ++t) {
        const size_t j0 = (size_t)t * 32;
        #define IK(m, p, G) gload16(G + xbase + (j0 + (p)*8)*DD + koff, &Ks[m][(p)*512])
        #define IV(m, p, G) gload16(G + vbase + (size_t)((p)*16)*SS + j0 + voff, &Vs[m][(p)*512])
        if (w == 0)      { IK(0,0,kmg); IK(0,1,kmg); IK(0,2,kmg); IK(0,3,kmg); IK(1,0,kvg); IK(1,1,kvg); }
        else if (w == 1) { IK(1,2,kvg); IK(1,3,kvg); IK(2,0,kkg); IK(2,1,kkg); IK(2,2,kkg); IK(2,3,kkg); }
        else if (w == 2) { IV(0,0,vtg); IV(0,1,vtg); IV(0,2,vtg); IV(0,3,vtg); IV(1,0,wtg); IV(1,1,wtg); }
        else             { IV(1,2,wtg); IV(1,3,wtg); IV(2,0,vvtg); IV(2,1,vvtg); IV(2,2,vvtg); IV(2,3,vvtg); }
        __syncthreads();

        #pragma unroll
        for (int jb = 0; jb < 2; ++jb) {
            f32x4 aa = {0.f,0.f,0.f,0.f}, vva = {0.f,0.f,0.f,0.f};
            const int j = jb*16 + lo;
            #pragma unroll
            for (int ks = 0; ks < 2; ++ks) {
                const int co = j*64 + (((ks*4 + hi) ^ (j & 7)) * 8);
                bf16x8 kB  = *(const bf16x8*)&Ks[0][co];
                bf16x8 vkB = *(const bf16x8*)&Ks[1][co];
                bf16x8 kkB = *(const bf16x8*)&Ks[2][co];
                aa  = MFMA16(qA[ks],  kB,  aa);
                vva = MFMA16(vqA[ks], kkB, vva);
                vva = MFMA16(qsA[ks], vkB, vva);
            }
            #pragma unroll
            for (int r = 0; r < 4; ++r) {
                float a  = aa[r]  * 0.03125f;
                float va = vva[r] * 0.0009765625f;
                float e  = __expf(a);
                float e2 = e*e;
                float ev = e2*va;
                float e3 = ev*e;
                const int pb = (hi*4 + r)*36 + jb*16 + lo;
                Ps[w][0][pb] = f2b(e);
                Ps[w][1][pb] = f2b(e2);
                Ps[w][2][pb] = f2b(ev);
                Ps[w][3][pb] = f2b(e3);
            }
        }

        {
            const int pa = lo*36 + hi*8;
            bf16x8 eA  = *(const bf16x8*)&Ps[w][0][pa];
            bf16x8 e2A = *(const bf16x8*)&Ps[w][1][pa];
            bf16x8 evA = *(const bf16x8*)&Ps[w][2][pa];
            bf16x8 e3A = *(const bf16x8*)&Ps[w][3][pa];
            zac   = MFMA16(eA,  onesB, zac);
            e2vac = MFMA16(evA, onesB, e2vac);
            #pragma unroll
            for (int cb = 0; cb < 4; ++cb) {
                const int d = cb*16 + lo;
                const int vo_ = d*32 + ((hi ^ (d & 3)) * 8);
                bf16x8 vB  = *(const bf16x8*)&Vs[0][vo_];
                bf16x8 wB  = *(const bf16x8*)&Vs[1][vo_];
                bf16x8 vvB = *(const bf16x8*)&Vs[2][vo_];
                T1[cb] = MFMA16(eA,  vB,  T1[cb]);
                T2[cb] = MFMA16(evA, wB,  T2[cb]);
                T3[cb] = MFMA16(e3A, wB,  T3[cb]);
                T4[cb] = MFMA16(e2A, wB,  T4[cb]);
                T5[cb] = MFMA16(e2A, vvB, T5[cb]);
            }
        }
        __syncthreads();
    }

    #pragma unroll
    for (int r = 0; r < 4; ++r) {
        const float Z     = zac[r];
        const float invZ  = 1.f / Z;
        const float invZ2 = invZ * invZ;
        const float sv    = e2vac[r] * invZ2;
        const int row = qt*64 + w*16 + hi*4 + r;
        #pragma unroll
        for (int cb = 0; cb < 4; ++cb) {
            const size_t gi = xbase + (size_t)row*DD + cb*16 + lo;
            const float o  = T1[cb][r] * invZ;
            const float vo = (T2[cb][r] + sv*T4[cb][r] + T5[cb][r]) * invZ2
                           - 2.f * T3[cb][r] * invZ2 * invZ;
            om[gi] = x[gi] + o;
            ov[gi] = vx[gi] + vo;
        }
    }
}

extern "C" void kernel_launch(void* const* d_in, const int* in_sizes, int n_in,
                              void* d_out, int out_size, void* d_ws, size_t ws_size,
                              hipStream_t stream) {
    const float* x    = (const float*)d_in[0];
    const float* vx   = (const float*)d_in[1];
    const float* Wq   = (const float*)d_in[2];
    const float* vWq  = (const float*)d_in[3];
    const float* Wk   = (const float*)d_in[4];
    const float* vWk  = (const float*)d_in[5];
    const float* Wv   = (const float*)d_in[6];
    const float* vWv  = (const float*)d_in[7];

    const size_t NE = (size_t)MM * DD;
    const size_t NW = (size_t)DD * DD;

    unsigned short* u = (unsigned short*)d_ws;
    unsigned short* qm   = u + 0*NE;
    unsigned short* qv   = u + 1*NE;
    unsigned short* km   = u + 2*NE;
    unsigned short* kv   = u + 3*NE;
    unsigned short* vm   = u + 4*NE;
    unsigned short* vvv  = u + 5*NE;
    unsigned short* xbb  = u + 6*NE;   // after gemms: reused as vt
    unsigned short* vxbb = u + 7*NE;   // after gemms: reused as wt
    unsigned short* xsbb = u + 8*NE;   // after gemms: reused as vvt
    unsigned short* wp   = u + 9*NE;   // weights; after gemms: reused as kk
    unsigned short* wqb = wp + 0*NW, *wqc = wp + 1*NW, *wqv = wp + 2*NW;
    unsigned short* wkb = wp + 3*NW, *wkc = wp + 4*NW, *wkv = wp + 5*NW;
    unsigned short* wvb = wp + 6*NW, *wvc = wp + 7*NW, *wvv = wp + 8*NW;

    float* om = (float*)d_out;
    float* ov = om + NE;

    prep_x_kernel<<<4096, 256, 0, stream>>>(x, vx, xbb, vxbb, xsbb);
    prep_w_kernel<<<1024, 256, 0, stream>>>(Wq, vWq, wqb, wqc, wqv);
    prep_w_kernel<<<1024, 256, 0, stream>>>(Wk, vWk, wkb, wkc, wkv);
    prep_w_kernel<<<1024, 256, 0, stream>>>(Wv, vWv, wvb, wvc, wvv);

    dim3 gg(8, 32, 3);
    gemm_mean_kernel<<<gg, 256, 0, stream>>>(xbb, wqb, wkb, wvb, qm, km, vm);
    gemm_var_kernel<<<gg, 256, 0, stream>>>(vxbb, xsbb,
        wqc, wqv, wkc, wkv, wvc, wvv, qv, kv, vvv);

    unsigned short* vt  = xbb;
    unsigned short* wt  = vxbb;
    unsigned short* vvt = xsbb;
    unsigned short* kkb = wp;
    dim3 gt(SS/64, HH, BB);
    prep_vt_kernel<<<gt, 256, 0, stream>>>(vm, vvv, vt, wt, vvt);
    prep_kk_kernel<<<2048, 256, 0, stream>>>(km, kv, kkb);

    dim3 ga(SS/64, HH, BB);
    attn_mfma_kernel<<<ga, 256, 0, stream>>>(km, kv, kkb, vt, wt, vvt,
                                             qm, qv, x, vx, om, ov);
}

// Round 5
// 245.399 us; speedup vs baseline: 17.8443x; 1.2240x over previous
//
#include <hip/hip_runtime.h>
#include <hip/hip_bf16.h>

#define BB 4
#define SS 1024
#define DD 1024
#define HH 16
#define DH 64
#define MM (BB*SS)   // 4096

typedef __attribute__((ext_vector_type(8))) short bf16x8;
typedef __attribute__((ext_vector_type(8))) unsigned short u16x8;
typedef __attribute__((ext_vector_type(4))) float f32x4;

__device__ __forceinline__ float b2f(unsigned short u) {
    union { unsigned int i; float f; } c; c.i = ((unsigned int)u) << 16; return c.f;
}
__device__ __forceinline__ unsigned short f2b(float f) {
    __hip_bfloat16 h = __float2bfloat16(f);
    return *reinterpret_cast<unsigned short*>(&h);
}
__device__ __forceinline__ unsigned int pack2(float a, float b) {
    return (unsigned int)f2b(a) | ((unsigned int)f2b(b) << 16);
}
__device__ __forceinline__ void gload16(const unsigned short* g, unsigned short* l) {
    __builtin_amdgcn_global_load_lds(
        (const __attribute__((address_space(1))) void*)g,
        (__attribute__((address_space(3))) void*)l,
        16, 0, 0);
}
#define MFMA16(a, b, c) __builtin_amdgcn_mfma_f32_16x16x32_bf16(a, b, c, 0, 0, 0)

// ---------------------------------------------------------------------------
// prep kernels (unchanged from R4 except prep_vt layout)
// ---------------------------------------------------------------------------
__global__ __launch_bounds__(256) void prep_x_kernel(
    const float* __restrict__ x, const float* __restrict__ vx,
    unsigned short* __restrict__ xb, unsigned short* __restrict__ vxb,
    unsigned short* __restrict__ xsb)
{
    const size_t i = ((size_t)blockIdx.x * 256 + threadIdx.x) * 4;
    float4 a = *(const float4*)(x + i);
    float4 b = *(const float4*)(vx + i);
    ushort4 oa = { f2b(a.x), f2b(a.y), f2b(a.z), f2b(a.w) };
    ushort4 ob = { f2b(b.x), f2b(b.y), f2b(b.z), f2b(b.w) };
    ushort4 os = { f2b(a.x*a.x), f2b(a.y*a.y), f2b(a.z*a.z), f2b(a.w*a.w) };
    *(ushort4*)(xb  + i) = oa;
    *(ushort4*)(vxb + i) = ob;
    *(ushort4*)(xsb + i) = os;
}

__global__ __launch_bounds__(256) void prep_w_kernel(
    const float* __restrict__ W, const float* __restrict__ vW,
    unsigned short* __restrict__ wb, unsigned short* __restrict__ wc,
    unsigned short* __restrict__ wv)
{
    const size_t i = ((size_t)blockIdx.x * 256 + threadIdx.x) * 4;
    float4 a = *(const float4*)(W + i);
    float4 b = *(const float4*)(vW + i);
    ushort4 oa = { f2b(a.x), f2b(a.y), f2b(a.z), f2b(a.w) };
    ushort4 oc = { f2b(a.x*a.x + b.x), f2b(a.y*a.y + b.y),
                   f2b(a.z*a.z + b.z), f2b(a.w*a.w + b.w) };
    ushort4 ov = { f2b(b.x), f2b(b.y), f2b(b.z), f2b(b.w) };
    *(ushort4*)(wb + i) = oa;
    *(ushort4*)(wc + i) = oc;
    *(ushort4*)(wv + i) = ov;
}

// ---------------------------------------------------------------------------
// Mean GEMM (m97 structure) — unchanged.
// ---------------------------------------------------------------------------
__global__ __launch_bounds__(256) void gemm_mean_kernel(
    const unsigned short* __restrict__ xb,
    const unsigned short* __restrict__ w0b, const unsigned short* __restrict__ w1b,
    const unsigned short* __restrict__ w2b,
    unsigned short* __restrict__ o0m, unsigned short* __restrict__ o1m,
    unsigned short* __restrict__ o2m)
{
    __shared__ unsigned short sA[128*32];
    __shared__ unsigned short sB[128*32];

    const int z = blockIdx.z;
    const unsigned short* Wb = (z==0)? w0b : (z==1)? w1b : w2b;
    unsigned short* Om = (z==0)? o0m : (z==1)? o1m : o2m;

    const int bn = blockIdx.x;
    const int bm = blockIdx.y;
    const int tid = threadIdx.x;
    const int w = tid >> 6;
    const int l = tid & 63;
    const int wr = w >> 1, wc = w & 1;

    const int c0 = w*64 + l;
    const int r0 = c0 >> 2, cc0 = (c0 & 3) * 8;
    const int c1 = c0 + 256;
    const int r1 = c1 >> 2, cc1 = (c1 & 3) * 8;

    const size_t aoff0 = (size_t)(bm*128 + r0) * DD + cc0;
    const size_t aoff1 = (size_t)(bm*128 + r1) * DD + cc1;
    const size_t boff0 = (size_t)(bn*128 + r0) * DD + cc0;
    const size_t boff1 = (size_t)(bn*128 + r1) * DD + cc1;

    const int lb0 = (w*64) * 8;
    const int lb1 = (256 + w*64) * 8;

    f32x4 acc[4][4];
    #pragma unroll
    for (int i = 0; i < 4; ++i)
        #pragma unroll
        for (int j = 0; j < 4; ++j)
            acc[i][j] = (f32x4){0.f,0.f,0.f,0.f};

    const int fr = l & 15;
    const int fk = (l >> 4) << 3;

    for (int kk = 0; kk < DD; kk += 32) {
        gload16(xb + aoff0 + kk, &sA[lb0]);
        gload16(xb + aoff1 + kk, &sA[lb1]);
        gload16(Wb + boff0 + kk, &sB[lb0]);
        gload16(Wb + boff1 + kk, &sB[lb1]);
        __syncthreads();

        bf16x8 bfr[4];
        #pragma unroll
        for (int j = 0; j < 4; ++j)
            bfr[j] = *(const bf16x8*)&sB[(wc*64 + j*16 + fr)*32 + fk];
        #pragma unroll
        for (int i = 0; i < 4; ++i) {
            bf16x8 a0 = *(const bf16x8*)&sA[(wr*64 + i*16 + fr)*32 + fk];
            #pragma unroll
            for (int j = 0; j < 4; ++j)
                acc[i][j] = MFMA16(a0, bfr[j], acc[i][j]);
        }
        __syncthreads();
    }

    const int orow = bm*128 + wr*64 + ((l >> 4) << 2);
    const int ocol = bn*128 + wc*64 + fr;
    #pragma unroll
    for (int i = 0; i < 4; ++i)
        #pragma unroll
        for (int j = 0; j < 4; ++j)
            #pragma unroll
            for (int r = 0; r < 4; ++r)
                Om[(size_t)(orow + i*16 + r) * DD + ocol + j*16] = f2b(acc[i][j][r]);
}

// ---------------------------------------------------------------------------
// Var GEMM (dual chain, single accumulator) — unchanged.
// ---------------------------------------------------------------------------
__global__ __launch_bounds__(256) void gemm_var_kernel(
    const unsigned short* __restrict__ vxb, const unsigned short* __restrict__ xsb,
    const unsigned short* __restrict__ w0c, const unsigned short* __restrict__ w0v,
    const unsigned short* __restrict__ w1c, const unsigned short* __restrict__ w1v,
    const unsigned short* __restrict__ w2c, const unsigned short* __restrict__ w2v,
    unsigned short* __restrict__ o0v, unsigned short* __restrict__ o1v,
    unsigned short* __restrict__ o2v)
{
    __shared__ unsigned short sA1[128*32];
    __shared__ unsigned short sA2[128*32];
    __shared__ unsigned short sB1[128*32];
    __shared__ unsigned short sB2[128*32];

    const int z = blockIdx.z;
    const unsigned short* Wc = (z==0)? w0c : (z==1)? w1c : w2c;
    const unsigned short* Wv = (z==0)? w0v : (z==1)? w1v : w2v;
    unsigned short* Ov = (z==0)? o0v : (z==1)? o1v : o2v;

    const int bn = blockIdx.x;
    const int bm = blockIdx.y;
    const int tid = threadIdx.x;
    const int w = tid >> 6;
    const int l = tid & 63;
    const int wr = w >> 1, wc = w & 1;

    const int c0 = w*64 + l;
    const int r0 = c0 >> 2, cc0 = (c0 & 3) * 8;
    const int c1 = c0 + 256;
    const int r1 = c1 >> 2, cc1 = (c1 & 3) * 8;

    const size_t aoff0 = (size_t)(bm*128 + r0) * DD + cc0;
    const size_t aoff1 = (size_t)(bm*128 + r1) * DD + cc1;
    const size_t boff0 = (size_t)(bn*128 + r0) * DD + cc0;
    const size_t boff1 = (size_t)(bn*128 + r1) * DD + cc1;

    const int lb0 = (w*64) * 8;
    const int lb1 = (256 + w*64) * 8;

    f32x4 acc[4][4];
    #pragma unroll
    for (int i = 0; i < 4; ++i)
        #pragma unroll
        for (int j = 0; j < 4; ++j)
            acc[i][j] = (f32x4){0.f,0.f,0.f,0.f};

    const int fr = l & 15;
    const int fk = (l >> 4) << 3;

    for (int kk = 0; kk < DD; kk += 32) {
        gload16(vxb + aoff0 + kk, &sA1[lb0]);
        gload16(vxb + aoff1 + kk, &sA1[lb1]);
        gload16(xsb + aoff0 + kk, &sA2[lb0]);
        gload16(xsb + aoff1 + kk, &sA2[lb1]);
        gload16(Wc + boff0 + kk, &sB1[lb0]);
        gload16(Wc + boff1 + kk, &sB1[lb1]);
        gload16(Wv + boff0 + kk, &sB2[lb0]);
        gload16(Wv + boff1 + kk, &sB2[lb1]);
        __syncthreads();

        bf16x8 bc[4], bv[4];
        #pragma unroll
        for (int j = 0; j < 4; ++j) {
            const int bo = (wc*64 + j*16 + fr)*32 + fk;
            bc[j] = *(const bf16x8*)&sB1[bo];
            bv[j] = *(const bf16x8*)&sB2[bo];
        }
        #pragma unroll
        for (int i = 0; i < 4; ++i) {
            const int ao = (wr*64 + i*16 + fr)*32 + fk;
            bf16x8 a1 = *(const bf16x8*)&sA1[ao];
            bf16x8 a2 = *(const bf16x8*)&sA2[ao];
            #pragma unroll
            for (int j = 0; j < 4; ++j) {
                acc[i][j] = MFMA16(a1, bc[j], acc[i][j]);
                acc[i][j] = MFMA16(a2, bv[j], acc[i][j]);
            }
        }
        __syncthreads();
    }

    const int orow = bm*128 + wr*64 + ((l >> 4) << 2);
    const int ocol = bn*128 + wc*64 + fr;
    #pragma unroll
    for (int i = 0; i < 4; ++i)
        #pragma unroll
        for (int j = 0; j < 4; ++j)
            #pragma unroll
            for (int r = 0; r < 4; ++r)
                Ov[(size_t)(orow + i*16 + r) * DD + ocol + j*16] = f2b(acc[i][j][r]);
}

// ---------------------------------------------------------------------------
// prep_vt: V-side -> [B*H][DH][SS] with per-32-col tile in PERMUTED+SWIZZLED
// order: physical (d, t*32 + pc*8 + e) holds logical j = t*32 +
//   (e>>2)*16 + (pc ^ ((d>>1)&3))*4 + (e&3).
// This makes the attention PV B-fragment a single conflict-free ds_read_b128.
// ---------------------------------------------------------------------------
__global__ __launch_bounds__(256) void prep_vt_kernel(
    const unsigned short* __restrict__ vm, const unsigned short* __restrict__ vvv,
    unsigned short* __restrict__ vt, unsigned short* __restrict__ wt,
    unsigned short* __restrict__ vvt)
{
    __shared__ unsigned short tv[64][68];
    __shared__ unsigned short tw[64][68];
    __shared__ unsigned short tvv[64][68];
    const int t = threadIdx.x;
    const int jt = blockIdx.x, h = blockIdx.y, b = blockIdx.z;
    const size_t ibase = (size_t)b*SS*DD + (size_t)h*DH;
    {
        const int j = t & 63, cg = t >> 6;
        const size_t ga = ibase + (size_t)(jt*64 + j)*DD + cg*16;
        #pragma unroll
        for (int hh = 0; hh < 2; ++hh) {
            u16x8 v8  = *(const u16x8*)(vm  + ga + hh*8);
            u16x8 vv8 = *(const u16x8*)(vvv + ga + hh*8);
            u16x8 w8;
            #pragma unroll
            for (int e = 0; e < 8; ++e) {
                float vf = b2f(v8[e]);
                w8[e] = f2b(b2f(vv8[e]) + vf*vf);
            }
            *(u16x8*)&tv[j][cg*16 + hh*8]  = v8;
            *(u16x8*)&tvv[j][cg*16 + hh*8] = vv8;
            *(u16x8*)&tw[j][cg*16 + hh*8]  = w8;
        }
    }
    __syncthreads();
    {
        const int d  = t >> 2;
        const int pc = t & 3;
        const int lc = pc ^ ((d >> 1) & 3);
        #pragma unroll
        for (int st = 0; st < 2; ++st) {
            u16x8 o0, o1, o2;
            #pragma unroll
            for (int e = 0; e < 8; ++e) {
                const int jl = st*32 + (e >> 2)*16 + lc*4 + (e & 3);
                o0[e] = tv[jl][d];
                o1[e] = tw[jl][d];
                o2[e] = tvv[jl][d];
            }
            const size_t ob = (size_t)((b*HH + h)*DH + d)*SS + jt*64 + st*32 + pc*8;
            *(u16x8*)(vt  + ob) = o0;
            *(u16x8*)(wt  + ob) = o1;
            *(u16x8*)(vvt + ob) = o2;
        }
    }
}

// kk = vk + k^2 (elementwise bf16)
__global__ __launch_bounds__(256) void prep_kk_kernel(
    const unsigned short* __restrict__ kmp, const unsigned short* __restrict__ kvp,
    unsigned short* __restrict__ kkb)
{
    const size_t i = ((size_t)blockIdx.x * 256 + threadIdx.x) * 8;
    u16x8 k8 = *(const u16x8*)(kmp + i);
    u16x8 v8 = *(const u16x8*)(kvp + i);
    u16x8 o8;
    #pragma unroll
    for (int e = 0; e < 8; ++e) {
        float kf = b2f(k8[e]);
        o8[e] = f2b(b2f(v8[e]) + kf*kf);
    }
    *(u16x8*)(kkb + i) = o8;
}

// ---------------------------------------------------------------------------
// MFMA attention VMP + residual, v2:
//  - swapped QK (A=K, B=Q) so P lives in registers as the PV A-fragment
//    under permuted-k order sigma(hi,e) = (e>>2)*16 + hi*4 + (e&3)
//  - V global layout pre-permuted+swizzled (prep_vt) -> PV B-frag = 1x b128
//  - double-buffered K/V staging via global_load_lds (prefetch t+1)
//  - no P LDS; LDS = 48KB -> 3 blocks/CU
// Grid: 1024 blocks (XCD-chunked swizzle), 4 waves, wave w owns 16 q-rows.
// ---------------------------------------------------------------------------
union PW { unsigned int u[4]; bf16x8 v; };

__global__ __launch_bounds__(256, 3) void attn_mfma_kernel(
    const unsigned short* __restrict__ kmg, const unsigned short* __restrict__ kvg,
    const unsigned short* __restrict__ kkg,
    const unsigned short* __restrict__ vtg, const unsigned short* __restrict__ wtg,
    const unsigned short* __restrict__ vvtg,
    const unsigned short* __restrict__ qmg, const unsigned short* __restrict__ qvg,
    const float* __restrict__ x, const float* __restrict__ vx,
    float* __restrict__ om, float* __restrict__ ov)
{
    __shared__ unsigned short Ks[2][3][32*64];
    __shared__ unsigned short Vs[2][3][64*32];

    const int tid = threadIdx.x;
    const int w = tid >> 6, l = tid & 63;
    const int lo = l & 15, hi = l >> 4;

    // XCD-chunked decode: all 16 q-tiles of one (b,h) share an XCD slot
    const int fb = blockIdx.x;
    const int g  = ((fb >> 7) << 3) | (fb & 7);   // 0..63 = b*16+h
    const int qt = (fb >> 3) & 15;
    const int h  = g & 15;
    const int b  = g >> 4;

    const size_t xbase = (size_t)b*SS*DD + (size_t)h*DH;
    const size_t vbase = (size_t)(b*HH + h)*DH*SS;

    // Q fragments (lane holds Q[q=lo][d = ks*32 + hi*8 + e]) — serve as the
    // B-operand of the swapped QK MFMA.
    bf16x8 qA[2], vqA[2], qsA[2];
    {
        const int qrow = qt*64 + w*16 + lo;
        #pragma unroll
        for (int ks = 0; ks < 2; ++ks) {
            const size_t ga = xbase + (size_t)qrow*DD + ks*32 + hi*8;
            qA[ks]  = *(const bf16x8*)(qmg + ga);
            vqA[ks] = *(const bf16x8*)(qvg + ga);
            #pragma unroll
            for (int e = 0; e < 8; ++e) {
                float f = b2f((unsigned short)qA[ks][e]);
                qsA[ks][e] = (short)f2b(f*f);
            }
        }
    }
    bf16x8 onesB;
    #pragma unroll
    for (int e = 0; e < 8; ++e) onesB[e] = (short)0x3F80;

    f32x4 T1[4], T2[4], T3[4], T4[4], T5[4];
    f32x4 zac = {0.f,0.f,0.f,0.f}, e2vac = {0.f,0.f,0.f,0.f};
    #pragma unroll
    for (int cb = 0; cb < 4; ++cb) {
        T1[cb] = (f32x4){0.f,0.f,0.f,0.f};
        T2[cb] = (f32x4){0.f,0.f,0.f,0.f};
        T3[cb] = (f32x4){0.f,0.f,0.f,0.f};
        T4[cb] = (f32x4){0.f,0.f,0.f,0.f};
        T5[cb] = (f32x4){0.f,0.f,0.f,0.f};
    }

    // staging source offsets (K globals pre-swizzle applied per-lane;
    // V globals already permuted+swizzled in memory)
    const size_t koff = (size_t)(l >> 3)*DD + (size_t)(((l & 7) ^ ((l >> 3) & 7)) * 8);
    const size_t voff = (size_t)(l >> 2)*SS + (size_t)((l & 3) * 8);

    const float INV_RD  = 0.03125f;
    const float INV_RD2 = 0.0009765625f;

#define IK(bu, m, p, G) gload16(G + xbase + (j0 + (size_t)(p)*8)*DD + koff, &Ks[bu][m][(p)*512])
#define IV(bu, m, p, G) gload16(G + vbase + (size_t)((p)*16)*SS + j0 + voff, &Vs[bu][m][(p)*512])
#define STAGE(tt, bu) do {                                                     \
        const size_t j0 = (size_t)(tt) * 32;                                   \
        if (w == 0)      { IK(bu,0,0,kmg); IK(bu,0,1,kmg); IK(bu,0,2,kmg);     \
                           IK(bu,0,3,kmg); IK(bu,1,0,kvg); IK(bu,1,1,kvg); }   \
        else if (w == 1) { IK(bu,1,2,kvg); IK(bu,1,3,kvg); IK(bu,2,0,kkg);     \
                           IK(bu,2,1,kkg); IK(bu,2,2,kkg); IK(bu,2,3,kkg); }   \
        else if (w == 2) { IV(bu,0,0,vtg); IV(bu,0,1,vtg); IV(bu,0,2,vtg);     \
                           IV(bu,0,3,vtg); IV(bu,1,0,wtg); IV(bu,1,1,wtg); }   \
        else             { IV(bu,1,2,wtg); IV(bu,1,3,wtg); IV(bu,2,0,vvtg);    \
                           IV(bu,2,1,vvtg); IV(bu,2,2,vvtg); IV(bu,2,3,vvtg); }\
    } while (0)

    STAGE(0, 0);
    __syncthreads();

    int cur = 0;
    for (int t = 0; t < SS/32; ++t) {
        if (t + 1 < SS/32) STAGE(t + 1, cur ^ 1);

        // ---- QK (swapped) + moments -> in-register P fragments ----
        PW pe, pe2, pev, pe3;
        #pragma unroll
        for (int jb = 0; jb < 2; ++jb) {
            f32x4 aa = {0.f,0.f,0.f,0.f}, vva = {0.f,0.f,0.f,0.f};
            const int jrow = jb*16 + lo;
            #pragma unroll
            for (int ks = 0; ks < 2; ++ks) {
                const int co = jrow*64 + (((ks*4 + hi) ^ (lo & 7)) * 8);
                bf16x8 kB  = *(const bf16x8*)&Ks[cur][0][co];
                bf16x8 vkB = *(const bf16x8*)&Ks[cur][1][co];
                bf16x8 kkB = *(const bf16x8*)&Ks[cur][2][co];
                aa  = MFMA16(kB,  qA[ks],  aa);   // D[kv][q]
                vva = MFMA16(kkB, vqA[ks], vva);
                vva = MFMA16(vkB, qsA[ks], vva);
            }
            #pragma unroll
            for (int rp = 0; rp < 2; ++rp) {
                float a0 = aa[rp*2]   * INV_RD,  va0 = vva[rp*2]   * INV_RD2;
                float a1 = aa[rp*2+1] * INV_RD,  va1 = vva[rp*2+1] * INV_RD2;
                float e0 = __expf(a0), e1 = __expf(a1);
                float s0 = e0*e0,      s1 = e1*e1;
                float v0 = s0*va0,     v1 = s1*va1;
                float t0 = v0*e0,      t1 = v1*e1;
                pe.u [jb*2+rp] = pack2(e0, e1);
                pe2.u[jb*2+rp] = pack2(s0, s1);
                pev.u[jb*2+rp] = pack2(v0, v1);
                pe3.u[jb*2+rp] = pack2(t0, t1);
            }
        }

        // ---- PV (K=32 MFMA, permuted-k B-frags from swizzled Vs) ----
        zac   = MFMA16(pe.v,  onesB, zac);
        e2vac = MFMA16(pev.v, onesB, e2vac);
        #pragma unroll
        for (int cb = 0; cb < 4; ++cb) {
            const int vo = (cb*16 + lo)*32 + ((hi ^ ((lo >> 1) & 3)) * 8);
            bf16x8 vB  = *(const bf16x8*)&Vs[cur][0][vo];
            bf16x8 wB  = *(const bf16x8*)&Vs[cur][1][vo];
            bf16x8 vvB = *(const bf16x8*)&Vs[cur][2][vo];
            T1[cb] = MFMA16(pe.v,  vB,  T1[cb]);
            T2[cb] = MFMA16(pev.v, wB,  T2[cb]);
            T3[cb] = MFMA16(pe3.v, wB,  T3[cb]);
            T4[cb] = MFMA16(pe2.v, wB,  T4[cb]);
            T5[cb] = MFMA16(pe2.v, vvB, T5[cb]);
        }

        __syncthreads();
        cur ^= 1;
    }

    // epilogue: C/D row = hi*4+r = q-local, col = lo = d-col
    #pragma unroll
    for (int r = 0; r < 4; ++r) {
        const float Z     = zac[r];
        const float invZ  = 1.f / Z;
        const float invZ2 = invZ * invZ;
        const float sv    = e2vac[r] * invZ2;
        const int row = qt*64 + w*16 + hi*4 + r;
        #pragma unroll
        for (int cb = 0; cb < 4; ++cb) {
            const size_t gi = xbase + (size_t)row*DD + cb*16 + lo;
            const float o  = T1[cb][r] * invZ;
            const float vo = (T2[cb][r] + sv*T4[cb][r] + T5[cb][r]) * invZ2
                           - 2.f * T3[cb][r] * invZ2 * invZ;
            om[gi] = x[gi] + o;
            ov[gi] = vx[gi] + vo;
        }
    }
#undef IK
#undef IV
#undef STAGE
}

extern "C" void kernel_launch(void* const* d_in, const int* in_sizes, int n_in,
                              void* d_out, int out_size, void* d_ws, size_t ws_size,
                              hipStream_t stream) {
    const float* x    = (const float*)d_in[0];
    const float* vx   = (const float*)d_in[1];
    const float* Wq   = (const float*)d_in[2];
    const float* vWq  = (const float*)d_in[3];
    const float* Wk   = (const float*)d_in[4];
    const float* vWk  = (const float*)d_in[5];
    const float* Wv   = (const float*)d_in[6];
    const float* vWv  = (const float*)d_in[7];

    const size_t NE = (size_t)MM * DD;
    const size_t NW = (size_t)DD * DD;

    unsigned short* u = (unsigned short*)d_ws;
    unsigned short* qm   = u + 0*NE;
    unsigned short* qv   = u + 1*NE;
    unsigned short* km   = u + 2*NE;
    unsigned short* kv   = u + 3*NE;
    unsigned short* vm   = u + 4*NE;
    unsigned short* vvv  = u + 5*NE;
    unsigned short* xbb  = u + 6*NE;   // after gemms: reused as vt
    unsigned short* vxbb = u + 7*NE;   // after gemms: reused as wt
    unsigned short* xsbb = u + 8*NE;   // after gemms: reused as vvt
    unsigned short* wp   = u + 9*NE;   // weights; after gemms: reused as kk
    unsigned short* wqb = wp + 0*NW, *wqc = wp + 1*NW, *wqv = wp + 2*NW;
    unsigned short* wkb = wp + 3*NW, *wkc = wp + 4*NW, *wkv = wp + 5*NW;
    unsigned short* wvb = wp + 6*NW, *wvc = wp + 7*NW, *wvv = wp + 8*NW;

    float* om = (float*)d_out;
    float* ov = om + NE;

    prep_x_kernel<<<4096, 256, 0, stream>>>(x, vx, xbb, vxbb, xsbb);
    prep_w_kernel<<<1024, 256, 0, stream>>>(Wq, vWq, wqb, wqc, wqv);
    prep_w_kernel<<<1024, 256, 0, stream>>>(Wk, vWk, wkb, wkc, wkv);
    prep_w_kernel<<<1024, 256, 0, stream>>>(Wv, vWv, wvb, wvc, wvv);

    dim3 gg(8, 32, 3);
    gemm_mean_kernel<<<gg, 256, 0, stream>>>(xbb, wqb, wkb, wvb, qm, km, vm);
    gemm_var_kernel<<<gg, 256, 0, stream>>>(vxbb, xsbb,
        wqc, wqv, wkc, wkv, wvc, wvv, qv, kv, vvv);

    unsigned short* vt  = xbb;
    unsigned short* wt  = vxbb;
    unsigned short* vvt = xsbb;
    unsigned short* kkb = wp;
    dim3 gt(SS/64, HH, BB);
    prep_vt_kernel<<<gt, 256, 0, stream>>>(vm, vvv, vt, wt, vvt);
    prep_kk_kernel<<<2048, 256, 0, stream>>>(km, kv, kkb);

    attn_mfma_kernel<<<1024, 256, 0, stream>>>(km, kv, kkb, vt, wt, vvt,
                                               qm, qv, x, vx, om, ov);
}

// Round 6
// 204.629 us; speedup vs baseline: 21.3996x; 1.1992x over previous
//
#include <hip/hip_runtime.h>
#include <hip/hip_bf16.h>

#define BB 4
#define SS 1024
#define DD 1024
#define HH 16
#define DH 64
#define MM (BB*SS)   // 4096

typedef __attribute__((ext_vector_type(8))) short bf16x8;
typedef __attribute__((ext_vector_type(8))) unsigned short u16x8;
typedef __attribute__((ext_vector_type(4))) float f32x4;

__device__ __forceinline__ float b2f(unsigned short u) {
    union { unsigned int i; float f; } c; c.i = ((unsigned int)u) << 16; return c.f;
}
__device__ __forceinline__ unsigned short f2b(float f) {
    __hip_bfloat16 h = __float2bfloat16(f);
    return *reinterpret_cast<unsigned short*>(&h);
}
__device__ __forceinline__ unsigned int pack2(float a, float b) {
    return (unsigned int)f2b(a) | ((unsigned int)f2b(b) << 16);
}
__device__ __forceinline__ void gload16(const unsigned short* g, unsigned short* l) {
    __builtin_amdgcn_global_load_lds(
        (const __attribute__((address_space(1))) void*)g,
        (__attribute__((address_space(3))) void*)l,
        16, 0, 0);
}
#define MFMA16(a, b, c) __builtin_amdgcn_mfma_f32_16x16x32_bf16(a, b, c, 0, 0, 0)

// ---------------------------------------------------------------------------
// prep_x: fp32 -> bf16 (x, vx, x^2)
// ---------------------------------------------------------------------------
__global__ __launch_bounds__(256) void prep_x_kernel(
    const float* __restrict__ x, const float* __restrict__ vx,
    unsigned short* __restrict__ xb, unsigned short* __restrict__ vxb,
    unsigned short* __restrict__ xsb)
{
    const size_t i = ((size_t)blockIdx.x * 256 + threadIdx.x) * 4;
    float4 a = *(const float4*)(x + i);
    float4 b = *(const float4*)(vx + i);
    ushort4 oa = { f2b(a.x), f2b(a.y), f2b(a.z), f2b(a.w) };
    ushort4 ob = { f2b(b.x), f2b(b.y), f2b(b.z), f2b(b.w) };
    ushort4 os = { f2b(a.x*a.x), f2b(a.y*a.y), f2b(a.z*a.z), f2b(a.w*a.w) };
    *(ushort4*)(xb  + i) = oa;
    *(ushort4*)(vxb + i) = ob;
    *(ushort4*)(xsb + i) = os;
}

// ---------------------------------------------------------------------------
// prep_w: all three weight sets in one dispatch (z = blockIdx.y).
// wp layout: [3*z + {b,c,v}] * NW   (b = W, c = W*W+vW, v = vW)
// ---------------------------------------------------------------------------
__global__ __launch_bounds__(256) void prep_w_kernel(
    const float* __restrict__ W0, const float* __restrict__ vW0,
    const float* __restrict__ W1, const float* __restrict__ vW1,
    const float* __restrict__ W2, const float* __restrict__ vW2,
    unsigned short* __restrict__ wp)
{
    const int z = blockIdx.y;
    const float* W  = (z==0)? W0 : (z==1)? W1 : W2;
    const float* vW = (z==0)? vW0: (z==1)? vW1: vW2;
    const size_t NW = (size_t)DD*DD;
    unsigned short* wb = wp + (size_t)(3*z+0)*NW;
    unsigned short* wc = wp + (size_t)(3*z+1)*NW;
    unsigned short* wv = wp + (size_t)(3*z+2)*NW;

    const size_t i = ((size_t)blockIdx.x * 256 + threadIdx.x) * 4;
    float4 a = *(const float4*)(W + i);
    float4 b = *(const float4*)(vW + i);
    ushort4 oa = { f2b(a.x), f2b(a.y), f2b(a.z), f2b(a.w) };
    ushort4 oc = { f2b(a.x*a.x + b.x), f2b(a.y*a.y + b.y),
                   f2b(a.z*a.z + b.z), f2b(a.w*a.w + b.w) };
    ushort4 ov = { f2b(b.x), f2b(b.y), f2b(b.z), f2b(b.w) };
    *(ushort4*)(wb + i) = oa;
    *(ushort4*)(wc + i) = oc;
    *(ushort4*)(wv + i) = ov;
}

// ---------------------------------------------------------------------------
// Fused projection GEMM (one dispatch, z = 0..5):
//   z<3 : mean  m = xb @ W(z)^T                  K=1024 (NT=32)
//   z>=3: var   v = vxb @ Wc^T + xsb @ Wv^T      as K=2048 concat (NT=64)
// m97 structure + T3-min double-buffer (stage t+1 before compute t, one
// barrier per K-step) + both-sides LDS XOR swizzle chunk ^= (row>>1)&3.
// 128x128 tile, BK=32, 4 waves.
// ---------------------------------------------------------------------------
__global__ __launch_bounds__(256) void gemm_proj_kernel(
    const unsigned short* __restrict__ xb, const unsigned short* __restrict__ vxb,
    const unsigned short* __restrict__ xsb,
    const unsigned short* __restrict__ wp,
    unsigned short* __restrict__ qm, unsigned short* __restrict__ km,
    unsigned short* __restrict__ vm,
    unsigned short* __restrict__ qv, unsigned short* __restrict__ kv,
    unsigned short* __restrict__ vvv)
{
    __shared__ unsigned short sA[2][128*32];
    __shared__ unsigned short sB[2][128*32];

    const int z = blockIdx.z;
    const size_t NW = (size_t)DD*DD;
    const bool isVar = (z >= 3);
    const int p = isVar ? (z - 3) : z;
    const unsigned short* A0 = isVar ? vxb : xb;
    const unsigned short* A1 = isVar ? xsb : xb;
    const unsigned short* B0 = wp + (size_t)(3*p + (isVar ? 1 : 0)) * NW;
    const unsigned short* B1 = isVar ? (wp + (size_t)(3*p + 2) * NW) : B0;
    unsigned short* Out = (z==0)? qm : (z==1)? km : (z==2)? vm
                        : (z==3)? qv : (z==4)? kv : vvv;
    const int NT = isVar ? 64 : 32;

    const int bn = blockIdx.x;
    const int bm = blockIdx.y;
    const int tid = threadIdx.x;
    const int w = tid >> 6;
    const int l = tid & 63;
    const int wr = w >> 1, wc = w & 1;

    // staging: chunk c0 = tid (rows 0..63), c1 = tid+256 (rows 64..127)
    // source col-chunk = (c&3) ^ ((row>>1)&3)  (same for both loads)
    const int r0 = tid >> 2;
    const int s0 = (((tid & 3) ^ ((r0 >> 1) & 3)) * 8);
    const size_t aoff0 = (size_t)(bm*128 + r0) * DD + s0;
    const size_t boff0 = (size_t)(bn*128 + r0) * DD + s0;
    const int ldsd0 = (w*64) * 8;
    const int ldsd1 = (256 + w*64) * 8;

#define STG(buf, t) do {                                                   \
        const unsigned short* As_ = ((t) < 32) ? A0 : A1;                  \
        const unsigned short* Bs_ = ((t) < 32) ? B0 : B1;                  \
        const int kc_ = ((t) & 31) * 32;                                   \
        gload16(As_ + aoff0 + kc_,                   &sA[buf][ldsd0]);     \
        gload16(As_ + aoff0 + (size_t)64*DD + kc_,   &sA[buf][ldsd1]);     \
        gload16(Bs_ + boff0 + kc_,                   &sB[buf][ldsd0]);     \
        gload16(Bs_ + boff0 + (size_t)64*DD + kc_,   &sB[buf][ldsd1]);     \
    } while (0)

    f32x4 acc[4][4];
    #pragma unroll
    for (int i = 0; i < 4; ++i)
        #pragma unroll
        for (int j = 0; j < 4; ++j)
            acc[i][j] = (f32x4){0.f,0.f,0.f,0.f};

    const int fr = l & 15;
    const int hi = l >> 4;

    STG(0, 0);
    __syncthreads();

    for (int t = 0; t < NT; ++t) {
        const int cb = t & 1;
        if (t + 1 < NT) STG(cb ^ 1, t + 1);

        bf16x8 bfr[4];
        #pragma unroll
        for (int j = 0; j < 4; ++j) {
            const int row = wc*64 + j*16 + fr;
            bfr[j] = *(const bf16x8*)&sB[cb][row*32 + ((hi ^ ((row >> 1) & 3)) * 8)];
        }
        #pragma unroll
        for (int i = 0; i < 4; ++i) {
            const int row = wr*64 + i*16 + fr;
            bf16x8 a0 = *(const bf16x8*)&sA[cb][row*32 + ((hi ^ ((row >> 1) & 3)) * 8)];
            #pragma unroll
            for (int j = 0; j < 4; ++j)
                acc[i][j] = MFMA16(a0, bfr[j], acc[i][j]);
        }
        __syncthreads();
    }
#undef STG

    const int orow = bm*128 + wr*64 + (hi << 2);
    const int ocol = bn*128 + wc*64 + fr;
    #pragma unroll
    for (int i = 0; i < 4; ++i)
        #pragma unroll
        for (int j = 0; j < 4; ++j)
            #pragma unroll
            for (int r = 0; r < 4; ++r)
                Out[(size_t)(orow + i*16 + r) * DD + ocol + j*16] = f2b(acc[i][j][r]);
}

// ---------------------------------------------------------------------------
// prep_vt: V-side -> [B*H][DH][SS], permuted+swizzled (unchanged from R5).
// physical (d, t*32 + pc*8 + e) holds logical j = t*32 +
//   (e>>2)*16 + (pc ^ ((d>>1)&3))*4 + (e&3)
// ---------------------------------------------------------------------------
__global__ __launch_bounds__(256) void prep_vt_kernel(
    const unsigned short* __restrict__ vm, const unsigned short* __restrict__ vvv,
    unsigned short* __restrict__ vt, unsigned short* __restrict__ wt,
    unsigned short* __restrict__ vvt)
{
    __shared__ unsigned short tv[64][68];
    __shared__ unsigned short tw[64][68];
    __shared__ unsigned short tvv[64][68];
    const int t = threadIdx.x;
    const int jt = blockIdx.x, h = blockIdx.y, b = blockIdx.z;
    const size_t ibase = (size_t)b*SS*DD + (size_t)h*DH;
    {
        const int j = t & 63, cg = t >> 6;
        const size_t ga = ibase + (size_t)(jt*64 + j)*DD + cg*16;
        #pragma unroll
        for (int hh = 0; hh < 2; ++hh) {
            u16x8 v8  = *(const u16x8*)(vm  + ga + hh*8);
            u16x8 vv8 = *(const u16x8*)(vvv + ga + hh*8);
            u16x8 w8;
            #pragma unroll
            for (int e = 0; e < 8; ++e) {
                float vf = b2f(v8[e]);
                w8[e] = f2b(b2f(vv8[e]) + vf*vf);
            }
            *(u16x8*)&tv[j][cg*16 + hh*8]  = v8;
            *(u16x8*)&tvv[j][cg*16 + hh*8] = vv8;
            *(u16x8*)&tw[j][cg*16 + hh*8]  = w8;
        }
    }
    __syncthreads();
    {
        const int d  = t >> 2;
        const int pc = t & 3;
        const int lc = pc ^ ((d >> 1) & 3);
        #pragma unroll
        for (int st = 0; st < 2; ++st) {
            u16x8 o0, o1, o2;
            #pragma unroll
            for (int e = 0; e < 8; ++e) {
                const int jl = st*32 + (e >> 2)*16 + lc*4 + (e & 3);
                o0[e] = tv[jl][d];
                o1[e] = tw[jl][d];
                o2[e] = tvv[jl][d];
            }
            const size_t ob = (size_t)((b*HH + h)*DH + d)*SS + jt*64 + st*32 + pc*8;
            *(u16x8*)(vt  + ob) = o0;
            *(u16x8*)(wt  + ob) = o1;
            *(u16x8*)(vvt + ob) = o2;
        }
    }
}

// kk = vk + k^2 (elementwise bf16)
__global__ __launch_bounds__(256) void prep_kk_kernel(
    const unsigned short* __restrict__ kmp, const unsigned short* __restrict__ kvp,
    unsigned short* __restrict__ kkb)
{
    const size_t i = ((size_t)blockIdx.x * 256 + threadIdx.x) * 8;
    u16x8 k8 = *(const u16x8*)(kmp + i);
    u16x8 v8 = *(const u16x8*)(kvp + i);
    u16x8 o8;
    #pragma unroll
    for (int e = 0; e < 8; ++e) {
        float kf = b2f(k8[e]);
        o8[e] = f2b(b2f(v8[e]) + kf*kf);
    }
    *(u16x8*)(kkb + i) = o8;
}

// ---------------------------------------------------------------------------
// MFMA attention VMP + residual (unchanged from R5).
// ---------------------------------------------------------------------------
union PW { unsigned int u[4]; bf16x8 v; };

__global__ __launch_bounds__(256, 3) void attn_mfma_kernel(
    const unsigned short* __restrict__ kmg, const unsigned short* __restrict__ kvg,
    const unsigned short* __restrict__ kkg,
    const unsigned short* __restrict__ vtg, const unsigned short* __restrict__ wtg,
    const unsigned short* __restrict__ vvtg,
    const unsigned short* __restrict__ qmg, const unsigned short* __restrict__ qvg,
    const float* __restrict__ x, const float* __restrict__ vx,
    float* __restrict__ om, float* __restrict__ ov)
{
    __shared__ unsigned short Ks[2][3][32*64];
    __shared__ unsigned short Vs[2][3][64*32];

    const int tid = threadIdx.x;
    const int w = tid >> 6, l = tid & 63;
    const int lo = l & 15, hi = l >> 4;

    const int fb = blockIdx.x;
    const int g  = ((fb >> 7) << 3) | (fb & 7);
    const int qt = (fb >> 3) & 15;
    const int h  = g & 15;
    const int b  = g >> 4;

    const size_t xbase = (size_t)b*SS*DD + (size_t)h*DH;
    const size_t vbase = (size_t)(b*HH + h)*DH*SS;

    bf16x8 qA[2], vqA[2], qsA[2];
    {
        const int qrow = qt*64 + w*16 + lo;
        #pragma unroll
        for (int ks = 0; ks < 2; ++ks) {
            const size_t ga = xbase + (size_t)qrow*DD + ks*32 + hi*8;
            qA[ks]  = *(const bf16x8*)(qmg + ga);
            vqA[ks] = *(const bf16x8*)(qvg + ga);
            #pragma unroll
            for (int e = 0; e < 8; ++e) {
                float f = b2f((unsigned short)qA[ks][e]);
                qsA[ks][e] = (short)f2b(f*f);
            }
        }
    }
    bf16x8 onesB;
    #pragma unroll
    for (int e = 0; e < 8; ++e) onesB[e] = (short)0x3F80;

    f32x4 T1[4], T2[4], T3[4], T4[4], T5[4];
    f32x4 zac = {0.f,0.f,0.f,0.f}, e2vac = {0.f,0.f,0.f,0.f};
    #pragma unroll
    for (int cb = 0; cb < 4; ++cb) {
        T1[cb] = (f32x4){0.f,0.f,0.f,0.f};
        T2[cb] = (f32x4){0.f,0.f,0.f,0.f};
        T3[cb] = (f32x4){0.f,0.f,0.f,0.f};
        T4[cb] = (f32x4){0.f,0.f,0.f,0.f};
        T5[cb] = (f32x4){0.f,0.f,0.f,0.f};
    }

    const size_t koff = (size_t)(l >> 3)*DD + (size_t)(((l & 7) ^ ((l >> 3) & 7)) * 8);
    const size_t voff = (size_t)(l >> 2)*SS + (size_t)((l & 3) * 8);

    const float INV_RD  = 0.03125f;
    const float INV_RD2 = 0.0009765625f;

#define IK(bu, m, p, G) gload16(G + xbase + (j0 + (size_t)(p)*8)*DD + koff, &Ks[bu][m][(p)*512])
#define IV(bu, m, p, G) gload16(G + vbase + (size_t)((p)*16)*SS + j0 + voff, &Vs[bu][m][(p)*512])
#define STAGE(tt, bu) do {                                                     \
        const size_t j0 = (size_t)(tt) * 32;                                   \
        if (w == 0)      { IK(bu,0,0,kmg); IK(bu,0,1,kmg); IK(bu,0,2,kmg);     \
                           IK(bu,0,3,kmg); IK(bu,1,0,kvg); IK(bu,1,1,kvg); }   \
        else if (w == 1) { IK(bu,1,2,kvg); IK(bu,1,3,kvg); IK(bu,2,0,kkg);     \
                           IK(bu,2,1,kkg); IK(bu,2,2,kkg); IK(bu,2,3,kkg); }   \
        else if (w == 2) { IV(bu,0,0,vtg); IV(bu,0,1,vtg); IV(bu,0,2,vtg);     \
                           IV(bu,0,3,vtg); IV(bu,1,0,wtg); IV(bu,1,1,wtg); }   \
        else             { IV(bu,1,2,wtg); IV(bu,1,3,wtg); IV(bu,2,0,vvtg);    \
                           IV(bu,2,1,vvtg); IV(bu,2,2,vvtg); IV(bu,2,3,vvtg); }\
    } while (0)

    STAGE(0, 0);
    __syncthreads();

    int cur = 0;
    for (int t = 0; t < SS/32; ++t) {
        if (t + 1 < SS/32) STAGE(t + 1, cur ^ 1);

        PW pe, pe2, pev, pe3;
        #pragma unroll
        for (int jb = 0; jb < 2; ++jb) {
            f32x4 aa = {0.f,0.f,0.f,0.f}, vva = {0.f,0.f,0.f,0.f};
            const int jrow = jb*16 + lo;
            #pragma unroll
            for (int ks = 0; ks < 2; ++ks) {
                const int co = jrow*64 + (((ks*4 + hi) ^ (lo & 7)) * 8);
                bf16x8 kB  = *(const bf16x8*)&Ks[cur][0][co];
                bf16x8 vkB = *(const bf16x8*)&Ks[cur][1][co];
                bf16x8 kkB = *(const bf16x8*)&Ks[cur][2][co];
                aa  = MFMA16(kB,  qA[ks],  aa);
                vva = MFMA16(kkB, vqA[ks], vva);
                vva = MFMA16(vkB, qsA[ks], vva);
            }
            #pragma unroll
            for (int rp = 0; rp < 2; ++rp) {
                float a0 = aa[rp*2]   * INV_RD,  va0 = vva[rp*2]   * INV_RD2;
                float a1 = aa[rp*2+1] * INV_RD,  va1 = vva[rp*2+1] * INV_RD2;
                float e0 = __expf(a0), e1 = __expf(a1);
                float s0 = e0*e0,      s1 = e1*e1;
                float v0 = s0*va0,     v1 = s1*va1;
                float t0 = v0*e0,      t1 = v1*e1;
                pe.u [jb*2+rp] = pack2(e0, e1);
                pe2.u[jb*2+rp] = pack2(s0, s1);
                pev.u[jb*2+rp] = pack2(v0, v1);
                pe3.u[jb*2+rp] = pack2(t0, t1);
            }
        }

        zac   = MFMA16(pe.v,  onesB, zac);
        e2vac = MFMA16(pev.v, onesB, e2vac);
        #pragma unroll
        for (int cb = 0; cb < 4; ++cb) {
            const int vo = (cb*16 + lo)*32 + ((hi ^ ((lo >> 1) & 3)) * 8);
            bf16x8 vB  = *(const bf16x8*)&Vs[cur][0][vo];
            bf16x8 wB  = *(const bf16x8*)&Vs[cur][1][vo];
            bf16x8 vvB = *(const bf16x8*)&Vs[cur][2][vo];
            T1[cb] = MFMA16(pe.v,  vB,  T1[cb]);
            T2[cb] = MFMA16(pev.v, wB,  T2[cb]);
            T3[cb] = MFMA16(pe3.v, wB,  T3[cb]);
            T4[cb] = MFMA16(pe2.v, wB,  T4[cb]);
            T5[cb] = MFMA16(pe2.v, vvB, T5[cb]);
        }

        __syncthreads();
        cur ^= 1;
    }

    #pragma unroll
    for (int r = 0; r < 4; ++r) {
        const float Z     = zac[r];
        const float invZ  = 1.f / Z;
        const float invZ2 = invZ * invZ;
        const float sv    = e2vac[r] * invZ2;
        const int row = qt*64 + w*16 + hi*4 + r;
        #pragma unroll
        for (int cb = 0; cb < 4; ++cb) {
            const size_t gi = xbase + (size_t)row*DD + cb*16 + lo;
            const float o  = T1[cb][r] * invZ;
            const float vo = (T2[cb][r] + sv*T4[cb][r] + T5[cb][r]) * invZ2
                           - 2.f * T3[cb][r] * invZ2 * invZ;
            om[gi] = x[gi] + o;
            ov[gi] = vx[gi] + vo;
        }
    }
#undef IK
#undef IV
#undef STAGE
}

extern "C" void kernel_launch(void* const* d_in, const int* in_sizes, int n_in,
                              void* d_out, int out_size, void* d_ws, size_t ws_size,
                              hipStream_t stream) {
    const float* x    = (const float*)d_in[0];
    const float* vx   = (const float*)d_in[1];
    const float* Wq   = (const float*)d_in[2];
    const float* vWq  = (const float*)d_in[3];
    const float* Wk   = (const float*)d_in[4];
    const float* vWk  = (const float*)d_in[5];
    const float* Wv   = (const float*)d_in[6];
    const float* vWv  = (const float*)d_in[7];

    const size_t NE = (size_t)MM * DD;
    const size_t NW = (size_t)DD * DD;

    unsigned short* u = (unsigned short*)d_ws;
    unsigned short* qm   = u + 0*NE;
    unsigned short* qv   = u + 1*NE;
    unsigned short* km   = u + 2*NE;
    unsigned short* kv   = u + 3*NE;
    unsigned short* vm   = u + 4*NE;
    unsigned short* vvv  = u + 5*NE;
    unsigned short* xbb  = u + 6*NE;   // after gemms: reused as vt
    unsigned short* vxbb = u + 7*NE;   // after gemms: reused as wt
    unsigned short* xsbb = u + 8*NE;   // after gemms: reused as vvt
    unsigned short* wp   = u + 9*NE;   // 9 weight mats; after gemms: reused as kk

    float* om = (float*)d_out;
    float* ov = om + NE;

    prep_x_kernel<<<4096, 256, 0, stream>>>(x, vx, xbb, vxbb, xsbb);
    prep_w_kernel<<<dim3(1024, 3), 256, 0, stream>>>(Wq, vWq, Wk, vWk, Wv, vWv, wp);

    dim3 gg(8, 32, 6);
    gemm_proj_kernel<<<gg, 256, 0, stream>>>(xbb, vxbb, xsbb, wp,
                                             qm, km, vm, qv, kv, vvv);

    unsigned short* vt  = xbb;
    unsigned short* wt  = vxbb;
    unsigned short* vvt = xsbb;
    unsigned short* kkb = wp;
    dim3 gt(SS/64, HH, BB);
    prep_vt_kernel<<<gt, 256, 0, stream>>>(vm, vvv, vt, wt, vvt);
    prep_kk_kernel<<<2048, 256, 0, stream>>>(km, kv, kkb);

    attn_mfma_kernel<<<1024, 256, 0, stream>>>(km, kv, kkb, vt, wt, vvt,
                                               qm, qv, x, vx, om, ov);
}